// Round 1
// baseline (1003.488 us; speedup 1.0000x reference)
//
#include <hip/hip_runtime.h>
#include <hip/hip_bf16.h>
#include <math.h>

#define NN 20000
#define DD 128
#define CC1 256
#define CC2 32

// ---------------- CSR build ----------------
__global__ void k_count(const int* __restrict__ dst, int* __restrict__ cnt, int E) {
    int e = blockIdx.x * blockDim.x + threadIdx.x;
    if (e < E) atomicAdd(&cnt[dst[e]], 1);
}

__global__ void k_scan(const int* __restrict__ cnt, int* __restrict__ offs, int n) {
    __shared__ int part[1024];
    int t = threadIdx.x;
    int chunk = (n + 1023) / 1024;
    int lo = t * chunk, hi = min(lo + chunk, n);
    int s = 0;
    for (int i = lo; i < hi; i++) s += cnt[i];
    part[t] = s;
    __syncthreads();
    for (int d = 1; d < 1024; d <<= 1) {
        int v = (t >= d) ? part[t - d] : 0;
        __syncthreads();
        part[t] += v;
        __syncthreads();
    }
    int base = (t > 0) ? part[t - 1] : 0;
    for (int i = lo; i < hi; i++) { offs[i] = base; base += cnt[i]; }
    if (t == 1023) offs[n] = part[1023];
}

__global__ void k_fill(const int* __restrict__ src, const int* __restrict__ dst,
                       const int* __restrict__ offs, int* __restrict__ fill,
                       int* __restrict__ csr_src, int E) {
    int e = blockIdx.x * blockDim.x + threadIdx.x;
    if (e < E) {
        int d = dst[e];
        int pos = atomicAdd(&fill[d], 1);
        csr_src[offs[d] + pos] = src[e];
    }
}

// ---------------- fold attW1 through Wa1 ----------------
// fold[0..127] = Wa1 @ attW1[:256]; fold[128..255] = Wa1 @ attW1[256:]; fold[256] = ba1.attW1[:256]+ba1.attW1[256:]+attb1
__global__ void k_fold(const float* __restrict__ Wa1, const float* __restrict__ ba1,
                       const float* __restrict__ attW1, const float* __restrict__ attb1,
                       float* __restrict__ fold) {
    int t = threadIdx.x; // 128
    float vs = 0.f, vd = 0.f;
    for (int k = 0; k < CC1; k++) {
        float w = Wa1[t * CC1 + k];
        vs += w * attW1[k];
        vd += w * attW1[CC1 + k];
    }
    fold[t] = vs;
    fold[128 + t] = vd;
    if (t == 0) {
        float c = attb1[0];
        for (int k = 0; k < CC1; k++) c += ba1[k] * (attW1[k] + attW1[CC1 + k]);
        fold[256] = c;
    }
}

// ---------------- per-dst mean aggregation (one wave per node) ----------------
__global__ __launch_bounds__(256) void k_seg_mean(const float* __restrict__ in,
                                                  const int* __restrict__ offs,
                                                  const int* __restrict__ csr_src,
                                                  float* __restrict__ out, int n) {
    int wave = (blockIdx.x * blockDim.x + threadIdx.x) >> 6;
    int lane = threadIdx.x & 63;
    if (wave >= n) return;
    int lo = offs[wave], hi = offs[wave + 1];
    const float2* f2 = (const float2*)in;
    float2 acc = make_float2(0.f, 0.f);
    for (int i = lo; i < hi; i++) {
        int s = csr_src[i];
        float2 v = f2[(size_t)s * 64 + lane];
        acc.x += v.x; acc.y += v.y;
    }
    float inv = 1.0f / (float)max(hi - lo, 1);
    acc.x *= inv; acc.y *= inv;
    ((float2*)out)[(size_t)wave * 64 + lane] = acc;
}

// ---------------- row GEMM [n,128]x[128,128], fused epilogues ----------------
// MODE 0: L2-normalize rows -> out
// MODE 1: out = z1; also a_src = row.fold_s, a_dst = row.fold_d
template <int MODE>
__global__ __launch_bounds__(256) void k_gemm128(const float* __restrict__ in,
                                                 const float* __restrict__ W,
                                                 const float* __restrict__ b,
                                                 float* __restrict__ out,
                                                 const float* __restrict__ fold,
                                                 float* __restrict__ a_src,
                                                 float* __restrict__ a_dst,
                                                 int n, int rows_per_block) {
    __shared__ float sW[128 * 128];
    __shared__ float srow[2][128];
    __shared__ float swa[4], swb[4];
    int t = threadIdx.x;
    for (int i = t; i < 128 * 128; i += 256) sW[i] = W[i];
    int half = t >> 7;
    int j = t & 127;
    float bj = b[j];
    float vs = 0.f, vd = 0.f;
    if (MODE == 1) { vs = fold[j]; vd = fold[128 + j]; }
    int row0 = blockIdx.x * rows_per_block;
    int row_end = min(row0 + rows_per_block, n);
    for (int r = row0; r < row_end; r += 2) {
        __syncthreads();
        int rr = r + half;
        if (rr < row_end) srow[half][j] = in[(size_t)rr * 128 + j];
        __syncthreads();
        int myrow = r + half;
        bool active = (myrow < row_end);
        float acc = bj;
        if (active) {
            #pragma unroll 8
            for (int k = 0; k < 128; k++) acc += srow[half][k] * sW[k * 128 + j];
        }
        if (MODE == 0) {
            float ss = active ? acc * acc : 0.f;
            for (int o = 32; o > 0; o >>= 1) ss += __shfl_xor(ss, o);
            int wv = t >> 6;
            if ((t & 63) == 0) swa[wv] = ss;
            __syncthreads();
            float tot = swa[half * 2] + swa[half * 2 + 1];
            if (active) {
                float scale = 1.0f / fmaxf(sqrtf(tot), 1e-12f);
                out[(size_t)myrow * 128 + j] = acc * scale;
            }
        } else {
            if (active) out[(size_t)myrow * 128 + j] = acc;
            float ps = active ? acc * vs : 0.f;
            float pd = active ? acc * vd : 0.f;
            for (int o = 32; o > 0; o >>= 1) { ps += __shfl_xor(ps, o); pd += __shfl_xor(pd, o); }
            int wv = t >> 6;
            if ((t & 63) == 0) { swa[wv] = ps; swb[wv] = pd; }
            __syncthreads();
            if (active && j == 0) {
                a_src[myrow] = swa[half * 2] + swa[half * 2 + 1];
                a_dst[myrow] = swb[half * 2] + swb[half * 2 + 1];
            }
        }
    }
}

// ---------------- sparse GAT core (one wave per dst): r = (sum a*z1[src]) / sum a ----------------
__global__ __launch_bounds__(256) void k_att(const float* __restrict__ z1,
                                             const int* __restrict__ offs,
                                             const int* __restrict__ csr_src,
                                             const float* __restrict__ a_src,
                                             const float* __restrict__ a_dst,
                                             const float* __restrict__ fold,
                                             float* __restrict__ r, int n) {
    int wave = (blockIdx.x * blockDim.x + threadIdx.x) >> 6;
    int lane = threadIdx.x & 63;
    if (wave >= n) return;
    int lo = offs[wave], hi = offs[wave + 1];
    float C0 = fold[256] + a_dst[wave];
    // pass 1: max (edge-parallel)
    float m = -1e30f;
    for (int i = lo + lane; i < hi; i += 64) {
        float e = a_src[csr_src[i]] + C0;
        e = e > 0.f ? e : 0.01f * e;
        m = fmaxf(m, e);
    }
    for (int o = 32; o > 0; o >>= 1) m = fmaxf(m, __shfl_xor(m, o));
    // pass 2: denom (edge-parallel)
    float den = 0.f;
    for (int i = lo + lane; i < hi; i += 64) {
        float e = a_src[csr_src[i]] + C0;
        e = e > 0.f ? e : 0.01f * e;
        den += __expf(e - m);
    }
    for (int o = 32; o > 0; o >>= 1) den += __shfl_xor(den, o);
    float invden = 1.0f / den;
    // pass 3: channel-parallel weighted sum
    const float2* z2p = (const float2*)z1;
    float2 acc = make_float2(0.f, 0.f);
    for (int i = lo; i < hi; i++) {
        int s = csr_src[i];
        float e = a_src[s] + C0;
        e = e > 0.f ? e : 0.01f * e;
        float al = __expf(e - m);
        float2 v = z2p[(size_t)s * 64 + lane];
        acc.x += al * v.x; acc.y += al * v.y;
    }
    ((float2*)r)[(size_t)wave * 64 + lane] = make_float2(acc.x * invden, acc.y * invden);
}

// ---------------- s1 = softmax(r @ Wa1 + ba1) ----------------
__global__ __launch_bounds__(256) void k_s1(const float* __restrict__ r,
                                            const float* __restrict__ Wa1,
                                            const float* __restrict__ ba1,
                                            float* __restrict__ s1, int n, int rows_per_block) {
    __shared__ float sW[128 * 256];
    __shared__ float srow[128];
    __shared__ float sred[4];
    __shared__ float sred2[4];
    int t = threadIdx.x;
    for (int i = t; i < 128 * 256; i += 256) sW[i] = Wa1[i];
    float bj = ba1[t];
    int row0 = blockIdx.x * rows_per_block;
    int row_end = min(row0 + rows_per_block, n);
    for (int row = row0; row < row_end; row++) {
        __syncthreads();
        if (t < 128) srow[t] = r[(size_t)row * 128 + t];
        __syncthreads();
        float acc = bj;
        #pragma unroll 8
        for (int k = 0; k < 128; k++) acc += srow[k] * sW[k * 256 + t];
        float mx = acc;
        for (int o = 32; o > 0; o >>= 1) mx = fmaxf(mx, __shfl_xor(mx, o));
        if ((t & 63) == 0) sred[t >> 6] = mx;
        __syncthreads();
        mx = fmaxf(fmaxf(sred[0], sred[1]), fmaxf(sred[2], sred[3]));
        float ex = __expf(acc - mx);
        float sm = ex;
        for (int o = 32; o > 0; o >>= 1) sm += __shfl_xor(sm, o);
        if ((t & 63) == 0) sred2[t >> 6] = sm;
        __syncthreads();
        sm = sred2[0] + sred2[1] + sred2[2] + sred2[3];
        s1[(size_t)row * 256 + t] = ex / sm;
    }
}

// ---------------- x1 = s1^T @ z1, split-K with per-thread register column ----------------
__global__ __launch_bounds__(256) void k_x1(const float* __restrict__ s1,
                                            const float* __restrict__ z1,
                                            float* __restrict__ x1, int n, int rows_per_block) {
    __shared__ float sz[128];
    int t = threadIdx.x;
    float acc[128];
    #pragma unroll
    for (int d = 0; d < 128; d++) acc[d] = 0.f;
    int row0 = blockIdx.x * rows_per_block;
    int row_end = min(row0 + rows_per_block, n);
    for (int i = row0; i < row_end; i++) {
        __syncthreads();
        if (t < 128) sz[t] = z1[(size_t)i * 128 + t];
        __syncthreads();
        float sc = s1[(size_t)i * 256 + t];
        #pragma unroll
        for (int d = 0; d < 128; d++) acc[d] += sc * sz[d];
    }
    for (int d = 0; d < 128; d++) atomicAdd(&x1[t * 128 + d], acc[d]);
}

// ---------------- lin2 = x1 @ We2 + be2 ----------------
__global__ __launch_bounds__(256) void k_lin2(const float* __restrict__ x1,
                                              const float* __restrict__ We2,
                                              const float* __restrict__ be2,
                                              float* __restrict__ lin2) {
    int half = threadIdx.x >> 7, j = threadIdx.x & 127;
    int row = blockIdx.x * 2 + half;
    __shared__ float sr[2][128];
    sr[half][j] = x1[row * 128 + j];
    __syncthreads();
    float acc = be2[j];
    #pragma unroll 8
    for (int k = 0; k < 128; k++) acc += sr[half][k] * We2[k * 128 + j];
    lin2[row * 128 + j] = acc;
}

// ---------------- coarse level: mrow, zrow, softmax p; s2, x2, embed0, assign1 ----------------
__global__ void k_coarse(const float* __restrict__ lin2, const float* __restrict__ Wa2,
                         const float* __restrict__ ba2,
                         float* __restrict__ s2, float* __restrict__ assign1,
                         float* __restrict__ x2, float* __restrict__ embed0) {
    __shared__ float mrow[128];
    __shared__ float p[32];
    __shared__ float red[2];
    int t = threadIdx.x; // 128 threads
    float s = 0.f;
    for (int i = 0; i < 256; i++) s += lin2[i * 128 + t];
    mrow[t] = s / 256.0f;
    __syncthreads();
    if (t < 32) {
        float z = ba2[t];
        for (int d = 0; d < 128; d++) z += mrow[d] * Wa2[d * 32 + t];
        float mx = z;
        for (int o = 16; o > 0; o >>= 1) mx = fmaxf(mx, __shfl_xor(mx, o, 32));
        float ex = __expf(z - mx);
        float sm = ex;
        for (int o = 16; o > 0; o >>= 1) sm += __shfl_xor(sm, o, 32);
        p[t] = ex / sm;
        assign1[t] = 1.0f;
    }
    __syncthreads();
    for (int i = t; i < 256 * 32; i += 128) s2[i] = p[i & 31];
    for (int i = t; i < 32 * 128; i += 128) {
        int k = i >> 7, d = i & 127;
        x2[i] = 256.0f * p[k] * mrow[d];
    }
    float tot = 0.f;
    for (int i = t; i < 32 * 128; i += 128) {
        int k = i >> 7, d = i & 127;
        tot += 256.0f * p[k] * mrow[d];
    }
    for (int o = 32; o > 0; o >>= 1) tot += __shfl_xor(tot, o);
    if ((t & 63) == 0) red[t >> 6] = tot;
    __syncthreads();
    if (t == 0) embed0[0] = (red[0] + red[1]) / 4096.0f;
}

extern "C" void kernel_launch(void* const* d_in, const int* in_sizes, int n_in,
                              void* d_out, int out_size, void* d_ws, size_t ws_size,
                              hipStream_t stream) {
    const float* feature = (const float*)d_in[0];
    const int*   eidx    = (const int*)d_in[1];
    const float* Wf   = (const float*)d_in[2];
    const float* bf   = (const float*)d_in[3];
    const float* We1  = (const float*)d_in[4];
    const float* be1  = (const float*)d_in[5];
    const float* Wa1  = (const float*)d_in[6];
    const float* ba1  = (const float*)d_in[7];
    const float* attW1= (const float*)d_in[8];
    const float* attb1= (const float*)d_in[9];
    const float* We2  = (const float*)d_in[10];
    const float* be2  = (const float*)d_in[11];
    const float* Wa2  = (const float*)d_in[12];
    const float* ba2  = (const float*)d_in[13];

    const int N = in_sizes[0] / DD;     // 20000
    const int E = in_sizes[1] / 2;      // 340000
    const int* src = eidx;
    const int* dst = eidx + E;

    // d_out layout
    float* out = (float*)d_out;
    float* s1_o      = out;
    float* s2_o      = s1_o + (size_t)N * CC1;
    float* assign1_o = s2_o + CC1 * CC2;
    float* embed3_o  = assign1_o + CC2;
    float* x1_o      = embed3_o + (size_t)N * DD;
    float* x2_o      = x1_o + CC1 * DD;
    float* embed0_o  = x2_o + CC2 * DD;

    // workspace carve
    char* w = (char*)d_ws;
    auto alloc = [&](size_t bytes) { void* p = (void*)w; w += ((bytes + 255) / 256) * 256; return p; };
    int* cnt   = (int*)alloc((size_t)N * 4);
    int* offs  = (int*)alloc((size_t)(N + 1) * 4);
    int* fill  = (int*)alloc((size_t)N * 4);
    int* csr   = (int*)alloc((size_t)E * 4);
    float* fold = (float*)alloc(257 * 4);
    float* agg  = (float*)alloc((size_t)N * DD * 4);   // reused: mean_f -> mean_x -> r
    float* z1   = (float*)alloc((size_t)N * DD * 4);
    float* a_src = (float*)alloc((size_t)N * 4);
    float* a_dst = (float*)alloc((size_t)N * 4);
    float* lin2  = (float*)alloc((size_t)CC1 * DD * 4);

    hipMemsetAsync(cnt, 0, (size_t)N * 4, stream);
    hipMemsetAsync(fill, 0, (size_t)N * 4, stream);
    hipMemsetAsync(x1_o, 0, (size_t)CC1 * DD * 4, stream);

    k_count<<<(E + 255) / 256, 256, 0, stream>>>(dst, cnt, E);
    k_scan<<<1, 1024, 0, stream>>>(cnt, offs, N);
    k_fill<<<(E + 255) / 256, 256, 0, stream>>>(src, dst, offs, fill, csr, E);
    k_fold<<<1, 128, 0, stream>>>(Wa1, ba1, attW1, attb1, fold);

    int segBlocks = (N + 3) / 4;
    // mean of feature over in-neighbors
    k_seg_mean<<<segBlocks, 256, 0, stream>>>(feature, offs, csr, agg, N);
    // x = normalize(mean_f @ Wf + bf)  -> embed3
    k_gemm128<0><<<(N + 15) / 16, 256, 0, stream>>>(agg, Wf, bf, embed3_o, nullptr, nullptr, nullptr, N, 16);
    // mean of x over in-neighbors
    k_seg_mean<<<segBlocks, 256, 0, stream>>>(embed3_o, offs, csr, agg, N);
    // z1 = mean_x @ We1 + be1 ; a_src/a_dst via folded attention vectors
    k_gemm128<1><<<(N + 15) / 16, 256, 0, stream>>>(agg, We1, be1, z1, fold, a_src, a_dst, N, 16);
    // sparse attention -> r (reuse agg)
    k_att<<<segBlocks, 256, 0, stream>>>(z1, offs, csr, a_src, a_dst, fold, agg, N);
    // s1 = softmax(r @ Wa1 + ba1)
    k_s1<<<(N + 15) / 16, 256, 0, stream>>>(agg, Wa1, ba1, s1_o, N, 16);
    // x1 = s1^T @ z1 (split-K 160, atomic accumulate)
    k_x1<<<160, 256, 0, stream>>>(s1_o, z1, x1_o, N, (N + 159) / 160);
    // lin2 = x1 @ We2 + be2
    k_lin2<<<CC1 / 2, 256, 0, stream>>>(x1_o, We2, be2, lin2);
    // coarse outputs
    k_coarse<<<1, 128, 0, stream>>>(lin2, Wa2, ba2, s2_o, assign1_o, x2_o, embed0_o);
}

// Round 3
// 410.904 us; speedup vs baseline: 2.4421x; 2.4421x over previous
//
#include <hip/hip_runtime.h>
#include <hip/hip_bf16.h>
#include <math.h>

#define NN 20000
#define DD 128
#define CC1 256
#define CC2 32
#define X1_SPLIT 128

// ---------------- CSR build ----------------
__global__ void k_count(const int* __restrict__ dst, int* __restrict__ cnt, int E) {
    int e = blockIdx.x * blockDim.x + threadIdx.x;
    if (e < E) atomicAdd(&cnt[dst[e]], 1);
}

__global__ void k_scan(const int* __restrict__ cnt, int* __restrict__ offs, int n) {
    __shared__ int part[1024];
    int t = threadIdx.x;
    int chunk = (n + 1023) / 1024;
    int lo = t * chunk, hi = min(lo + chunk, n);
    int s = 0;
    for (int i = lo; i < hi; i++) s += cnt[i];
    part[t] = s;
    __syncthreads();
    for (int d = 1; d < 1024; d <<= 1) {
        int v = (t >= d) ? part[t - d] : 0;
        __syncthreads();
        part[t] += v;
        __syncthreads();
    }
    int base = (t > 0) ? part[t - 1] : 0;
    for (int i = lo; i < hi; i++) { offs[i] = base; base += cnt[i]; }
    if (t == 1023) offs[n] = part[1023];
}

__global__ void k_fill(const int* __restrict__ src, const int* __restrict__ dst,
                       const int* __restrict__ offs, int* __restrict__ fill,
                       int* __restrict__ csr_src, int E) {
    int e = blockIdx.x * blockDim.x + threadIdx.x;
    if (e < E) {
        int d = dst[e];
        int pos = atomicAdd(&fill[d], 1);
        csr_src[offs[d] + pos] = src[e];
    }
}

// ---------------- fold attW1 through Wa1 ----------------
__global__ void k_fold(const float* __restrict__ Wa1, const float* __restrict__ ba1,
                       const float* __restrict__ attW1, const float* __restrict__ attb1,
                       float* __restrict__ fold) {
    int t = threadIdx.x; // 128
    float vs = 0.f, vd = 0.f;
    for (int k = 0; k < CC1; k++) {
        float w = Wa1[t * CC1 + k];
        vs += w * attW1[k];
        vd += w * attW1[CC1 + k];
    }
    fold[t] = vs;
    fold[128 + t] = vd;
    if (t == 0) {
        float c = attb1[0];
        for (int k = 0; k < CC1; k++) c += ba1[k] * (attW1[k] + attW1[CC1 + k]);
        fold[256] = c;
    }
}

// ---------------- per-dst mean aggregation (one wave per node, 2 edges in flight) ----------------
__global__ __launch_bounds__(256) void k_seg_mean(const float* __restrict__ in,
                                                  const int* __restrict__ offs,
                                                  const int* __restrict__ csr_src,
                                                  float* __restrict__ out, int n) {
    int wave = (blockIdx.x * blockDim.x + threadIdx.x) >> 6;
    int lane = threadIdx.x & 63;
    if (wave >= n) return;
    int lo = offs[wave], hi = offs[wave + 1];
    int half = lane >> 5, l32 = lane & 31;
    const float4* f4 = (const float4*)in;
    float4 acc = make_float4(0.f, 0.f, 0.f, 0.f);
    for (int i = lo + half; i < hi; i += 2) {
        int s = csr_src[i];
        float4 v = f4[(size_t)s * 32 + l32];
        acc.x += v.x; acc.y += v.y; acc.z += v.z; acc.w += v.w;
    }
    acc.x += __shfl_xor(acc.x, 32);
    acc.y += __shfl_xor(acc.y, 32);
    acc.z += __shfl_xor(acc.z, 32);
    acc.w += __shfl_xor(acc.w, 32);
    if (half == 0) {
        float inv = 1.0f / (float)max(hi - lo, 1);
        float4 r = make_float4(acc.x * inv, acc.y * inv, acc.z * inv, acc.w * inv);
        ((float4*)out)[(size_t)wave * 32 + l32] = r;
    }
}

// ---------------- row GEMM [n,128]x[128,128], 4x4 register tile, fused epilogues ----------------
// MODE 0: L2-normalize rows -> out
// MODE 1: out = z1; also a_src/a_dst via folded attention vectors
template <int MODE>
__global__ __launch_bounds__(256) void k_gemm128(const float* __restrict__ in,
                                                 const float* __restrict__ W,
                                                 const float* __restrict__ b,
                                                 float* __restrict__ out,
                                                 const float* __restrict__ fold,
                                                 float* __restrict__ a_src,
                                                 float* __restrict__ a_dst,
                                                 int n, int rows_per_block) {
    __shared__ float sW[128 * 128];   // 64 KB
    __shared__ float sT[128][32];     // 16 KB, transposed activations [k][lrow]
    int t = threadIdx.x;
    for (int i = t; i < 128 * 128; i += 256) sW[i] = W[i];
    int lane = t & 63;
    int wv = t >> 6;                  // 0..3
    int j4 = (lane & 31) * 4;         // col base
    int rh = lane >> 5;               // 0..1
    int rg = wv * 2 + rh;             // row subgroup 0..7 -> rows rg*4..rg*4+3
    float bj0 = b[j4], bj1 = b[j4 + 1], bj2 = b[j4 + 2], bj3 = b[j4 + 3];
    float vs0 = 0.f, vs1 = 0.f, vs2 = 0.f, vs3 = 0.f;
    float vd0 = 0.f, vd1 = 0.f, vd2 = 0.f, vd3 = 0.f;
    if (MODE == 1) {
        vs0 = fold[j4]; vs1 = fold[j4 + 1]; vs2 = fold[j4 + 2]; vs3 = fold[j4 + 3];
        vd0 = fold[128 + j4]; vd1 = fold[128 + j4 + 1]; vd2 = fold[128 + j4 + 2]; vd3 = fold[128 + j4 + 3];
    }
    int row0 = blockIdx.x * rows_per_block;
    int row_end = min(row0 + rows_per_block, n);
    for (int r = row0; r < row_end; r += 32) {
        int nr = min(32, row_end - r);
        __syncthreads();
        {
            int lrow = t >> 3, seg = t & 7;   // 32 rows x 8 segs of 16 k
            if (lrow < nr) {
                const float4* g = (const float4*)&in[(size_t)(r + lrow) * 128 + seg * 16];
                float4 v0 = g[0], v1 = g[1], v2 = g[2], v3 = g[3];
                int k0 = seg * 16;
                sT[k0 + 0][lrow] = v0.x; sT[k0 + 1][lrow] = v0.y; sT[k0 + 2][lrow] = v0.z; sT[k0 + 3][lrow] = v0.w;
                sT[k0 + 4][lrow] = v1.x; sT[k0 + 5][lrow] = v1.y; sT[k0 + 6][lrow] = v1.z; sT[k0 + 7][lrow] = v1.w;
                sT[k0 + 8][lrow] = v2.x; sT[k0 + 9][lrow] = v2.y; sT[k0 + 10][lrow] = v2.z; sT[k0 + 11][lrow] = v2.w;
                sT[k0 + 12][lrow] = v3.x; sT[k0 + 13][lrow] = v3.y; sT[k0 + 14][lrow] = v3.z; sT[k0 + 15][lrow] = v3.w;
            }
        }
        __syncthreads();
        float acc[4][4];
        #pragma unroll
        for (int p = 0; p < 4; p++) { acc[p][0] = bj0; acc[p][1] = bj1; acc[p][2] = bj2; acc[p][3] = bj3; }
        for (int k = 0; k < 128; k++) {
            float4 w4 = *(const float4*)&sW[k * 128 + j4];
            float4 rv = *(const float4*)&sT[k][rg * 4];
            acc[0][0] += rv.x * w4.x; acc[0][1] += rv.x * w4.y; acc[0][2] += rv.x * w4.z; acc[0][3] += rv.x * w4.w;
            acc[1][0] += rv.y * w4.x; acc[1][1] += rv.y * w4.y; acc[1][2] += rv.y * w4.z; acc[1][3] += rv.y * w4.w;
            acc[2][0] += rv.z * w4.x; acc[2][1] += rv.z * w4.y; acc[2][2] += rv.z * w4.z; acc[2][3] += rv.z * w4.w;
            acc[3][0] += rv.w * w4.x; acc[3][1] += rv.w * w4.y; acc[3][2] += rv.w * w4.z; acc[3][3] += rv.w * w4.w;
        }
        #pragma unroll
        for (int p = 0; p < 4; p++) {
            int row = r + rg * 4 + p;
            if (MODE == 0) {
                float ss_ = acc[p][0] * acc[p][0] + acc[p][1] * acc[p][1] +
                            acc[p][2] * acc[p][2] + acc[p][3] * acc[p][3];
                ss_ += __shfl_xor(ss_, 16); ss_ += __shfl_xor(ss_, 8);
                ss_ += __shfl_xor(ss_, 4);  ss_ += __shfl_xor(ss_, 2); ss_ += __shfl_xor(ss_, 1);
                if (row < row_end) {
                    float scale = 1.0f / fmaxf(sqrtf(ss_), 1e-12f);
                    float4 o = make_float4(acc[p][0] * scale, acc[p][1] * scale, acc[p][2] * scale, acc[p][3] * scale);
                    *(float4*)&out[(size_t)row * 128 + j4] = o;
                }
            } else {
                if (row < row_end) {
                    float4 o = make_float4(acc[p][0], acc[p][1], acc[p][2], acc[p][3]);
                    *(float4*)&out[(size_t)row * 128 + j4] = o;
                }
                float ps = acc[p][0] * vs0 + acc[p][1] * vs1 + acc[p][2] * vs2 + acc[p][3] * vs3;
                float pd = acc[p][0] * vd0 + acc[p][1] * vd1 + acc[p][2] * vd2 + acc[p][3] * vd3;
                ps += __shfl_xor(ps, 16); ps += __shfl_xor(ps, 8); ps += __shfl_xor(ps, 4);
                ps += __shfl_xor(ps, 2);  ps += __shfl_xor(ps, 1);
                pd += __shfl_xor(pd, 16); pd += __shfl_xor(pd, 8); pd += __shfl_xor(pd, 4);
                pd += __shfl_xor(pd, 2);  pd += __shfl_xor(pd, 1);
                if (row < row_end && (lane & 31) == 0) {
                    a_src[row] = ps;
                    a_dst[row] = pd;
                }
            }
        }
    }
}

// ---------------- sparse GAT core (one wave per dst) ----------------
__global__ __launch_bounds__(256) void k_att(const float* __restrict__ z1,
                                             const int* __restrict__ offs,
                                             const int* __restrict__ csr_src,
                                             const float* __restrict__ a_src,
                                             const float* __restrict__ a_dst,
                                             const float* __restrict__ fold,
                                             float* __restrict__ r, int n) {
    int wave = (blockIdx.x * blockDim.x + threadIdx.x) >> 6;
    int lane = threadIdx.x & 63;
    if (wave >= n) return;
    int lo = offs[wave], hi = offs[wave + 1];
    float C0 = fold[256] + a_dst[wave];
    float m = -1e30f;
    for (int i = lo + lane; i < hi; i += 64) {
        float e = a_src[csr_src[i]] + C0;
        e = e > 0.f ? e : 0.01f * e;
        m = fmaxf(m, e);
    }
    for (int o = 32; o > 0; o >>= 1) m = fmaxf(m, __shfl_xor(m, o));
    float den = 0.f;
    for (int i = lo + lane; i < hi; i += 64) {
        float e = a_src[csr_src[i]] + C0;
        e = e > 0.f ? e : 0.01f * e;
        den += __expf(e - m);
    }
    for (int o = 32; o > 0; o >>= 1) den += __shfl_xor(den, o);
    float invden = 1.0f / den;
    // weighted sum: 2 edges in flight, float4 per half-wave
    int half = lane >> 5, l32 = lane & 31;
    const float4* z4 = (const float4*)z1;
    float4 acc = make_float4(0.f, 0.f, 0.f, 0.f);
    for (int i = lo + half; i < hi; i += 2) {
        int s = csr_src[i];
        float e = a_src[s] + C0;
        e = e > 0.f ? e : 0.01f * e;
        float al = __expf(e - m);
        float4 v = z4[(size_t)s * 32 + l32];
        acc.x += al * v.x; acc.y += al * v.y; acc.z += al * v.z; acc.w += al * v.w;
    }
    acc.x += __shfl_xor(acc.x, 32);
    acc.y += __shfl_xor(acc.y, 32);
    acc.z += __shfl_xor(acc.z, 32);
    acc.w += __shfl_xor(acc.w, 32);
    if (half == 0) {
        float4 o = make_float4(acc.x * invden, acc.y * invden, acc.z * invden, acc.w * invden);
        ((float4*)r)[(size_t)wave * 32 + l32] = o;
    }
}

// ---------------- s1 = softmax(r @ Wa1 + ba1), 4x4 register tile ----------------
__global__ __launch_bounds__(256) void k_s1(const float* __restrict__ r_,
                                            const float* __restrict__ Wa1,
                                            const float* __restrict__ ba1,
                                            float* __restrict__ s1, int n, int rows_per_block) {
    __shared__ float sW[128 * 256];   // 128 KB
    __shared__ float sT[128][16];     // 8 KB
    int t = threadIdx.x;
    for (int i = t; i < 128 * 256; i += 256) sW[i] = Wa1[i];
    int lane = t & 63, wv = t >> 6;   // wave wv handles rows wv*4..wv*4+3
    int j4 = lane * 4;                // cols 0..252
    float bj0 = ba1[j4], bj1 = ba1[j4 + 1], bj2 = ba1[j4 + 2], bj3 = ba1[j4 + 3];
    int row0 = blockIdx.x * rows_per_block;
    int row_end = min(row0 + rows_per_block, n);
    for (int r = row0; r < row_end; r += 16) {
        int nr = min(16, row_end - r);
        __syncthreads();
        {
            int lrow = t >> 4, seg = t & 15;  // 16 rows x 16 segs of 8 k
            if (lrow < nr) {
                const float4* g = (const float4*)&r_[(size_t)(r + lrow) * 128 + seg * 8];
                float4 v0 = g[0], v1 = g[1];
                int k0 = seg * 8;
                sT[k0 + 0][lrow] = v0.x; sT[k0 + 1][lrow] = v0.y; sT[k0 + 2][lrow] = v0.z; sT[k0 + 3][lrow] = v0.w;
                sT[k0 + 4][lrow] = v1.x; sT[k0 + 5][lrow] = v1.y; sT[k0 + 6][lrow] = v1.z; sT[k0 + 7][lrow] = v1.w;
            }
        }
        __syncthreads();
        float acc[4][4];
        #pragma unroll
        for (int p = 0; p < 4; p++) { acc[p][0] = bj0; acc[p][1] = bj1; acc[p][2] = bj2; acc[p][3] = bj3; }
        for (int k = 0; k < 128; k++) {
            float4 w4 = *(const float4*)&sW[k * 256 + j4];
            float4 rv = *(const float4*)&sT[k][wv * 4];
            acc[0][0] += rv.x * w4.x; acc[0][1] += rv.x * w4.y; acc[0][2] += rv.x * w4.z; acc[0][3] += rv.x * w4.w;
            acc[1][0] += rv.y * w4.x; acc[1][1] += rv.y * w4.y; acc[1][2] += rv.y * w4.z; acc[1][3] += rv.y * w4.w;
            acc[2][0] += rv.z * w4.x; acc[2][1] += rv.z * w4.y; acc[2][2] += rv.z * w4.z; acc[2][3] += rv.z * w4.w;
            acc[3][0] += rv.w * w4.x; acc[3][1] += rv.w * w4.y; acc[3][2] += rv.w * w4.z; acc[3][3] += rv.w * w4.w;
        }
        #pragma unroll
        for (int p = 0; p < 4; p++) {
            int row = r + wv * 4 + p;
            float mx = fmaxf(fmaxf(acc[p][0], acc[p][1]), fmaxf(acc[p][2], acc[p][3]));
            mx = fmaxf(mx, __shfl_xor(mx, 32)); mx = fmaxf(mx, __shfl_xor(mx, 16));
            mx = fmaxf(mx, __shfl_xor(mx, 8));  mx = fmaxf(mx, __shfl_xor(mx, 4));
            mx = fmaxf(mx, __shfl_xor(mx, 2));  mx = fmaxf(mx, __shfl_xor(mx, 1));
            float e0 = __expf(acc[p][0] - mx), e1 = __expf(acc[p][1] - mx);
            float e2 = __expf(acc[p][2] - mx), e3 = __expf(acc[p][3] - mx);
            float sm = e0 + e1 + e2 + e3;
            sm += __shfl_xor(sm, 32); sm += __shfl_xor(sm, 16); sm += __shfl_xor(sm, 8);
            sm += __shfl_xor(sm, 4);  sm += __shfl_xor(sm, 2);  sm += __shfl_xor(sm, 1);
            if (row < row_end) {
                float inv = 1.0f / sm;
                float4 o = make_float4(e0 * inv, e1 * inv, e2 * inv, e3 * inv);
                *(float4*)&s1[(size_t)row * 256 + j4] = o;
            }
        }
    }
}

// ---------------- x1 = s1^T @ z1, split-K partials (no spill, no atomics) ----------------
__global__ __launch_bounds__(1024) void k_x1(const float* __restrict__ s1,
                                             const float* __restrict__ z1,
                                             float* __restrict__ part, int n) {
    __shared__ float ss[8][256];
    __shared__ float sz[8][128];
    int t = threadIdx.x;
    int c2 = t & 127;          // column pair: 2*c2, 2*c2+1
    int dg = t >> 7;           // 0..7 (wave-uniform pairs)
    int d0 = dg * 16;
    float a0[16], a1[16];
    #pragma unroll
    for (int q = 0; q < 16; q++) { a0[q] = 0.f; a1[q] = 0.f; }
    int rows_per_block = (n + X1_SPLIT - 1) / X1_SPLIT;
    int row0 = blockIdx.x * rows_per_block;
    int row_end = min(row0 + rows_per_block, n);
    for (int r = row0; r < row_end; r += 8) {
        int nb = min(8, row_end - r);
        __syncthreads();
        if (t < 512) {
            int lr = t >> 6, col4 = (t & 63) * 4;
            if (lr < nb) *(float4*)&ss[lr][col4] = *(const float4*)&s1[(size_t)(r + lr) * 256 + col4];
        } else if (t < 768) {
            int u = t - 512;
            int lr = u >> 5, col4 = (u & 31) * 4;
            if (lr < nb) *(float4*)&sz[lr][col4] = *(const float4*)&z1[(size_t)(r + lr) * 128 + col4];
        }
        __syncthreads();
        for (int i = 0; i < nb; i++) {
            float2 sv = *(const float2*)&ss[i][c2 * 2];
            const float4* zp = (const float4*)&sz[i][d0];
            #pragma unroll
            for (int q4 = 0; q4 < 4; q4++) {
                float4 zz = zp[q4];
                a0[q4 * 4 + 0] += sv.x * zz.x; a0[q4 * 4 + 1] += sv.x * zz.y;
                a0[q4 * 4 + 2] += sv.x * zz.z; a0[q4 * 4 + 3] += sv.x * zz.w;
                a1[q4 * 4 + 0] += sv.y * zz.x; a1[q4 * 4 + 1] += sv.y * zz.y;
                a1[q4 * 4 + 2] += sv.y * zz.z; a1[q4 * 4 + 3] += sv.y * zz.w;
            }
        }
    }
    size_t base = (size_t)blockIdx.x * 32768 + (size_t)(c2 * 2) * 128 + d0;
    #pragma unroll
    for (int q4 = 0; q4 < 4; q4++) {
        *(float4*)&part[base + q4 * 4] = make_float4(a0[q4 * 4], a0[q4 * 4 + 1], a0[q4 * 4 + 2], a0[q4 * 4 + 3]);
        *(float4*)&part[base + 128 + q4 * 4] = make_float4(a1[q4 * 4], a1[q4 * 4 + 1], a1[q4 * 4 + 2], a1[q4 * 4 + 3]);
    }
}

__global__ __launch_bounds__(256) void k_xred(const float* __restrict__ part,
                                              float* __restrict__ x1) {
    int o = blockIdx.x * 256 + threadIdx.x;   // 32768 outputs
    float s = 0.f;
    for (int p = 0; p < X1_SPLIT; p++) s += part[(size_t)p * 32768 + o];
    x1[o] = s;
}

// ---------------- lin2 = x1 @ We2 + be2 ----------------
__global__ __launch_bounds__(256) void k_lin2(const float* __restrict__ x1,
                                              const float* __restrict__ We2,
                                              const float* __restrict__ be2,
                                              float* __restrict__ lin2) {
    int half = threadIdx.x >> 7, j = threadIdx.x & 127;
    int row = blockIdx.x * 2 + half;
    __shared__ float sr[2][128];
    sr[half][j] = x1[row * 128 + j];
    __syncthreads();
    float acc = be2[j];
    #pragma unroll 8
    for (int k = 0; k < 128; k++) acc += sr[half][k] * We2[k * 128 + j];
    lin2[row * 128 + j] = acc;
}

// ---------------- coarse level ----------------
__global__ void k_coarse(const float* __restrict__ lin2, const float* __restrict__ Wa2,
                         const float* __restrict__ ba2,
                         float* __restrict__ s2, float* __restrict__ assign1,
                         float* __restrict__ x2, float* __restrict__ embed0) {
    __shared__ float mrow[128];
    __shared__ float p[32];
    __shared__ float red[2];
    int t = threadIdx.x; // 128 threads
    float s = 0.f;
    for (int i = 0; i < 256; i++) s += lin2[i * 128 + t];
    mrow[t] = s / 256.0f;
    __syncthreads();
    if (t < 32) {
        float z = ba2[t];
        for (int d = 0; d < 128; d++) z += mrow[d] * Wa2[d * 32 + t];
        float mx = z;
        for (int o = 16; o > 0; o >>= 1) mx = fmaxf(mx, __shfl_xor(mx, o, 32));
        float ex = __expf(z - mx);
        float sm = ex;
        for (int o = 16; o > 0; o >>= 1) sm += __shfl_xor(sm, o, 32);
        p[t] = ex / sm;
        assign1[t] = 1.0f;
    }
    __syncthreads();
    for (int i = t; i < 256 * 32; i += 128) s2[i] = p[i & 31];
    for (int i = t; i < 32 * 128; i += 128) {
        int k = i >> 7, d = i & 127;
        x2[i] = 256.0f * p[k] * mrow[d];
    }
    float tot = 0.f;
    for (int i = t; i < 32 * 128; i += 128) {
        int k = i >> 7, d = i & 127;
        tot += 256.0f * p[k] * mrow[d];
    }
    for (int o = 32; o > 0; o >>= 1) tot += __shfl_xor(tot, o);
    if ((t & 63) == 0) red[t >> 6] = tot;
    __syncthreads();
    if (t == 0) embed0[0] = (red[0] + red[1]) / 4096.0f;
}

extern "C" void kernel_launch(void* const* d_in, const int* in_sizes, int n_in,
                              void* d_out, int out_size, void* d_ws, size_t ws_size,
                              hipStream_t stream) {
    const float* feature = (const float*)d_in[0];
    const int*   eidx    = (const int*)d_in[1];
    const float* Wf   = (const float*)d_in[2];
    const float* bf   = (const float*)d_in[3];
    const float* We1  = (const float*)d_in[4];
    const float* be1  = (const float*)d_in[5];
    const float* Wa1  = (const float*)d_in[6];
    const float* ba1  = (const float*)d_in[7];
    const float* attW1= (const float*)d_in[8];
    const float* attb1= (const float*)d_in[9];
    const float* We2  = (const float*)d_in[10];
    const float* be2  = (const float*)d_in[11];
    const float* Wa2  = (const float*)d_in[12];
    const float* ba2  = (const float*)d_in[13];

    const int N = in_sizes[0] / DD;     // 20000
    const int E = in_sizes[1] / 2;      // 340000
    const int* src = eidx;
    const int* dst = eidx + E;

    // d_out layout
    float* out = (float*)d_out;
    float* s1_o      = out;
    float* s2_o      = s1_o + (size_t)N * CC1;
    float* assign1_o = s2_o + CC1 * CC2;
    float* embed3_o  = assign1_o + CC2;
    float* x1_o      = embed3_o + (size_t)N * DD;
    float* x2_o      = x1_o + CC1 * DD;
    float* embed0_o  = x2_o + CC2 * DD;

    // workspace carve
    char* w = (char*)d_ws;
    auto alloc = [&](size_t bytes) { void* p = (void*)w; w += ((bytes + 255) / 256) * 256; return p; };
    int* cnt   = (int*)alloc((size_t)N * 4);
    int* offs  = (int*)alloc((size_t)(N + 1) * 4);
    int* fill  = (int*)alloc((size_t)N * 4);
    int* csr   = (int*)alloc((size_t)E * 4);
    float* fold = (float*)alloc(257 * 4);
    float* z1   = (float*)alloc((size_t)N * DD * 4);
    float* a_src = (float*)alloc((size_t)N * 4);
    float* a_dst = (float*)alloc((size_t)N * 4);
    float* lin2  = (float*)alloc((size_t)CC1 * DD * 4);
    // agg region: reused as mean_f -> mean_x -> r, then OVERLAID by x1 partials
    size_t agg_bytes = (size_t)N * DD * 4;
    size_t part_bytes = (size_t)X1_SPLIT * CC1 * DD * 4;   // 16.78 MB
    float* agg  = (float*)alloc(agg_bytes > part_bytes ? agg_bytes : part_bytes);
    float* part = agg;   // agg is dead by the time k_x1 runs

    hipMemsetAsync(cnt, 0, (size_t)N * 4, stream);
    hipMemsetAsync(fill, 0, (size_t)N * 4, stream);

    k_count<<<(E + 255) / 256, 256, 0, stream>>>(dst, cnt, E);
    k_scan<<<1, 1024, 0, stream>>>(cnt, offs, N);
    k_fill<<<(E + 255) / 256, 256, 0, stream>>>(src, dst, offs, fill, csr, E);
    k_fold<<<1, 128, 0, stream>>>(Wa1, ba1, attW1, attb1, fold);

    int segBlocks = (N + 3) / 4;
    // mean of feature over in-neighbors
    k_seg_mean<<<segBlocks, 256, 0, stream>>>(feature, offs, csr, agg, N);
    // x = normalize(mean_f @ Wf + bf)  -> embed3
    k_gemm128<0><<<(N + 63) / 64, 256, 0, stream>>>(agg, Wf, bf, embed3_o, nullptr, nullptr, nullptr, N, 64);
    // mean of x over in-neighbors
    k_seg_mean<<<segBlocks, 256, 0, stream>>>(embed3_o, offs, csr, agg, N);
    // z1 = mean_x @ We1 + be1 ; a_src/a_dst via folded attention vectors
    k_gemm128<1><<<(N + 63) / 64, 256, 0, stream>>>(agg, We1, be1, z1, fold, a_src, a_dst, N, 64);
    // sparse attention -> r (reuse agg)
    k_att<<<segBlocks, 256, 0, stream>>>(z1, offs, csr, a_src, a_dst, fold, agg, N);
    // s1 = softmax(r @ Wa1 + ba1)
    k_s1<<<(N + 79) / 80, 256, 0, stream>>>(agg, Wa1, ba1, s1_o, N, 80);
    // x1 = s1^T @ z1 : split-K partials (overlaying agg), then reduce
    k_x1<<<X1_SPLIT, 1024, 0, stream>>>(s1_o, z1, part, N);
    k_xred<<<CC1 * DD / 256, 256, 0, stream>>>(part, x1_o);
    // lin2 = x1 @ We2 + be2
    k_lin2<<<CC1 / 2, 256, 0, stream>>>(x1_o, We2, be2, lin2);
    // coarse outputs
    k_coarse<<<1, 128, 0, stream>>>(lin2, Wa2, ba2, s2_o, assign1_o, x2_o, embed0_o);
}

// Round 4
// 381.233 us; speedup vs baseline: 2.6322x; 1.0778x over previous
//
#include <hip/hip_runtime.h>
#include <hip/hip_bf16.h>
#include <math.h>

#define NN 20000
#define DD 128
#define CC1 256
#define CC2 32
#define X1_SPLIT 128

__device__ __forceinline__ unsigned short f2bf(float f) {
    unsigned int b = __float_as_uint(f);
    b = (b + 0x7fffu + ((b >> 16) & 1u)) >> 16;
    return (unsigned short)b;
}
__device__ __forceinline__ float bf_lo(unsigned int u) { return __uint_as_float(u << 16); }
__device__ __forceinline__ float bf_hi(unsigned int u) { return __uint_as_float(u & 0xffff0000u); }

// ---------------- CSR build ----------------
__global__ void k_count(const int* __restrict__ dst, int* __restrict__ cnt, int E) {
    int e = blockIdx.x * blockDim.x + threadIdx.x;
    if (e < E) atomicAdd(&cnt[dst[e]], 1);
}

__global__ void k_scan(const int* __restrict__ cnt, int* __restrict__ offs, int n) {
    __shared__ int part[1024];
    int t = threadIdx.x;
    int chunk = (n + 1023) / 1024;
    int lo = t * chunk, hi = min(lo + chunk, n);
    int s = 0;
    for (int i = lo; i < hi; i++) s += cnt[i];
    part[t] = s;
    __syncthreads();
    for (int d = 1; d < 1024; d <<= 1) {
        int v = (t >= d) ? part[t - d] : 0;
        __syncthreads();
        part[t] += v;
        __syncthreads();
    }
    int base = (t > 0) ? part[t - 1] : 0;
    for (int i = lo; i < hi; i++) { offs[i] = base; base += cnt[i]; }
    if (t == 1023) offs[n] = part[1023];
}

__global__ void k_fill(const int* __restrict__ src, const int* __restrict__ dst,
                       const int* __restrict__ offs, int* __restrict__ fill,
                       int* __restrict__ csr_src, int E) {
    int e = blockIdx.x * blockDim.x + threadIdx.x;
    if (e < E) {
        int d = dst[e];
        int pos = atomicAdd(&fill[d], 1);
        csr_src[offs[d] + pos] = src[e];
    }
}

// ---------------- fold attW1 through Wa1 ----------------
__global__ void k_fold(const float* __restrict__ Wa1, const float* __restrict__ ba1,
                       const float* __restrict__ attW1, const float* __restrict__ attb1,
                       float* __restrict__ fold) {
    int t = threadIdx.x; // 128
    float vs = 0.f, vd = 0.f;
    for (int k = 0; k < CC1; k++) {
        float w = Wa1[t * CC1 + k];
        vs += w * attW1[k];
        vd += w * attW1[CC1 + k];
    }
    fold[t] = vs;
    fold[128 + t] = vd;
    if (t == 0) {
        float c = attb1[0];
        for (int k = 0; k < CC1; k++) c += ba1[k] * (attW1[k] + attW1[CC1 + k]);
        fold[256] = c;
    }
}

// ---------------- per-dst mean aggregation (one wave per node, 2 edges in flight, prefetch) ----------------
__global__ __launch_bounds__(256) void k_seg_mean(const float* __restrict__ in,
                                                  const int* __restrict__ offs,
                                                  const int* __restrict__ csr_src,
                                                  float* __restrict__ out, int n) {
    int wave = (blockIdx.x * blockDim.x + threadIdx.x) >> 6;
    int lane = threadIdx.x & 63;
    if (wave >= n) return;
    int lo = offs[wave], hi = offs[wave + 1];
    int half = lane >> 5, l32 = lane & 31;
    const float4* f4 = (const float4*)in;
    float4 acc = make_float4(0.f, 0.f, 0.f, 0.f);
    int i = lo + half;
    int sN = (i < hi) ? csr_src[i] : 0;
    while (i < hi) {
        int s = sN;
        int nx = i + 2;
        if (nx < hi) sN = csr_src[nx];
        float4 v = f4[(size_t)s * 32 + l32];
        acc.x += v.x; acc.y += v.y; acc.z += v.z; acc.w += v.w;
        i = nx;
    }
    acc.x += __shfl_xor(acc.x, 32);
    acc.y += __shfl_xor(acc.y, 32);
    acc.z += __shfl_xor(acc.z, 32);
    acc.w += __shfl_xor(acc.w, 32);
    if (half == 0) {
        float inv = 1.0f / (float)max(hi - lo, 1);
        float4 r = make_float4(acc.x * inv, acc.y * inv, acc.z * inv, acc.w * inv);
        ((float4*)out)[(size_t)wave * 32 + l32] = r;
    }
}

// ---------------- row GEMM [n,128]x[128,128], 4x4 register tile, fused epilogues ----------------
template <int MODE>
__global__ __launch_bounds__(256) void k_gemm128(const float* __restrict__ in,
                                                 const float* __restrict__ W,
                                                 const float* __restrict__ b,
                                                 float* __restrict__ out,
                                                 const float* __restrict__ fold,
                                                 float* __restrict__ a_src,
                                                 float* __restrict__ a_dst,
                                                 int n, int rows_per_block) {
    __shared__ float sW[128 * 128];   // 64 KB
    __shared__ float sT[128][32];     // 16 KB, transposed activations [k][lrow]
    int t = threadIdx.x;
    for (int i = t; i < 128 * 128; i += 256) sW[i] = W[i];
    int lane = t & 63;
    int wv = t >> 6;                  // 0..3
    int j4 = (lane & 31) * 4;         // col base
    int rh = lane >> 5;               // 0..1
    int rg = wv * 2 + rh;             // row subgroup 0..7
    float bj0 = b[j4], bj1 = b[j4 + 1], bj2 = b[j4 + 2], bj3 = b[j4 + 3];
    float vs0 = 0.f, vs1 = 0.f, vs2 = 0.f, vs3 = 0.f;
    float vd0 = 0.f, vd1 = 0.f, vd2 = 0.f, vd3 = 0.f;
    if (MODE == 1) {
        vs0 = fold[j4]; vs1 = fold[j4 + 1]; vs2 = fold[j4 + 2]; vs3 = fold[j4 + 3];
        vd0 = fold[128 + j4]; vd1 = fold[128 + j4 + 1]; vd2 = fold[128 + j4 + 2]; vd3 = fold[128 + j4 + 3];
    }
    int row0 = blockIdx.x * rows_per_block;
    int row_end = min(row0 + rows_per_block, n);
    for (int r = row0; r < row_end; r += 32) {
        int nr = min(32, row_end - r);
        __syncthreads();
        {
            int lrow = t >> 3, seg = t & 7;
            if (lrow < nr) {
                const float4* g = (const float4*)&in[(size_t)(r + lrow) * 128 + seg * 16];
                float4 v0 = g[0], v1 = g[1], v2 = g[2], v3 = g[3];
                int k0 = seg * 16;
                sT[k0 + 0][lrow] = v0.x; sT[k0 + 1][lrow] = v0.y; sT[k0 + 2][lrow] = v0.z; sT[k0 + 3][lrow] = v0.w;
                sT[k0 + 4][lrow] = v1.x; sT[k0 + 5][lrow] = v1.y; sT[k0 + 6][lrow] = v1.z; sT[k0 + 7][lrow] = v1.w;
                sT[k0 + 8][lrow] = v2.x; sT[k0 + 9][lrow] = v2.y; sT[k0 + 10][lrow] = v2.z; sT[k0 + 11][lrow] = v2.w;
                sT[k0 + 12][lrow] = v3.x; sT[k0 + 13][lrow] = v3.y; sT[k0 + 14][lrow] = v3.z; sT[k0 + 15][lrow] = v3.w;
            }
        }
        __syncthreads();
        float acc[4][4];
        #pragma unroll
        for (int p = 0; p < 4; p++) { acc[p][0] = bj0; acc[p][1] = bj1; acc[p][2] = bj2; acc[p][3] = bj3; }
        for (int k = 0; k < 128; k++) {
            float4 w4 = *(const float4*)&sW[k * 128 + j4];
            float4 rv = *(const float4*)&sT[k][rg * 4];
            acc[0][0] += rv.x * w4.x; acc[0][1] += rv.x * w4.y; acc[0][2] += rv.x * w4.z; acc[0][3] += rv.x * w4.w;
            acc[1][0] += rv.y * w4.x; acc[1][1] += rv.y * w4.y; acc[1][2] += rv.y * w4.z; acc[1][3] += rv.y * w4.w;
            acc[2][0] += rv.z * w4.x; acc[2][1] += rv.z * w4.y; acc[2][2] += rv.z * w4.z; acc[2][3] += rv.z * w4.w;
            acc[3][0] += rv.w * w4.x; acc[3][1] += rv.w * w4.y; acc[3][2] += rv.w * w4.z; acc[3][3] += rv.w * w4.w;
        }
        #pragma unroll
        for (int p = 0; p < 4; p++) {
            int row = r + rg * 4 + p;
            if (MODE == 0) {
                float ss_ = acc[p][0] * acc[p][0] + acc[p][1] * acc[p][1] +
                            acc[p][2] * acc[p][2] + acc[p][3] * acc[p][3];
                ss_ += __shfl_xor(ss_, 16); ss_ += __shfl_xor(ss_, 8);
                ss_ += __shfl_xor(ss_, 4);  ss_ += __shfl_xor(ss_, 2); ss_ += __shfl_xor(ss_, 1);
                if (row < row_end) {
                    float scale = 1.0f / fmaxf(sqrtf(ss_), 1e-12f);
                    float4 o = make_float4(acc[p][0] * scale, acc[p][1] * scale, acc[p][2] * scale, acc[p][3] * scale);
                    *(float4*)&out[(size_t)row * 128 + j4] = o;
                }
            } else {
                if (row < row_end) {
                    float4 o = make_float4(acc[p][0], acc[p][1], acc[p][2], acc[p][3]);
                    *(float4*)&out[(size_t)row * 128 + j4] = o;
                }
                float ps = acc[p][0] * vs0 + acc[p][1] * vs1 + acc[p][2] * vs2 + acc[p][3] * vs3;
                float pd = acc[p][0] * vd0 + acc[p][1] * vd1 + acc[p][2] * vd2 + acc[p][3] * vd3;
                ps += __shfl_xor(ps, 16); ps += __shfl_xor(ps, 8); ps += __shfl_xor(ps, 4);
                ps += __shfl_xor(ps, 2);  ps += __shfl_xor(ps, 1);
                pd += __shfl_xor(pd, 16); pd += __shfl_xor(pd, 8); pd += __shfl_xor(pd, 4);
                pd += __shfl_xor(pd, 2);  pd += __shfl_xor(pd, 1);
                if (row < row_end && (lane & 31) == 0) {
                    a_src[row] = ps;
                    a_dst[row] = pd;
                }
            }
        }
    }
}

// ---------------- sparse GAT core: single fused pass (no max; logits data-bounded ~O(1)) ----------------
__global__ __launch_bounds__(256) void k_att(const float* __restrict__ z1,
                                             const int* __restrict__ offs,
                                             const int* __restrict__ csr_src,
                                             const float* __restrict__ a_src,
                                             const float* __restrict__ a_dst,
                                             const float* __restrict__ fold,
                                             float* __restrict__ r, int n) {
    int wave = (blockIdx.x * blockDim.x + threadIdx.x) >> 6;
    int lane = threadIdx.x & 63;
    if (wave >= n) return;
    int lo = offs[wave], hi = offs[wave + 1];
    float C0 = fold[256] + a_dst[wave];
    int half = lane >> 5, l32 = lane & 31;
    const float4* z4 = (const float4*)z1;
    float4 acc = make_float4(0.f, 0.f, 0.f, 0.f);
    float den = 0.f;
    int i = lo + half;
    int sN = (i < hi) ? csr_src[i] : 0;
    while (i < hi) {
        int s = sN;
        int nx = i + 2;
        if (nx < hi) sN = csr_src[nx];
        float a = a_src[s];
        float4 v = z4[(size_t)s * 32 + l32];
        float e = a + C0;
        e = e > 0.f ? e : 0.01f * e;
        e = fminf(e, 60.f);           // overflow guard; data-bounded e ~ O(1)
        float al = __expf(e);
        den += al;
        acc.x += al * v.x; acc.y += al * v.y; acc.z += al * v.z; acc.w += al * v.w;
        i = nx;
    }
    den += __shfl_xor(den, 32);
    acc.x += __shfl_xor(acc.x, 32);
    acc.y += __shfl_xor(acc.y, 32);
    acc.z += __shfl_xor(acc.z, 32);
    acc.w += __shfl_xor(acc.w, 32);
    if (half == 0) {
        float invden = 1.0f / den;
        float4 o = make_float4(acc.x * invden, acc.y * invden, acc.z * invden, acc.w * invden);
        ((float4*)r)[(size_t)wave * 32 + l32] = o;
    }
}

// ---------------- s1 = softmax(r @ Wa1 + ba1): bf16 weights in LDS (80KB -> 2 blk/CU), 4rx8c tile ----------------
__global__ __launch_bounds__(256) void k_s1(const float* __restrict__ r_,
                                            const float* __restrict__ Wa1,
                                            const float* __restrict__ ba1,
                                            float* __restrict__ s1, int n, int rows_per_block) {
    __shared__ unsigned short sW2[128 * 256];  // 64 KB bf16
    __shared__ float sT[128][32];              // 16 KB
    int t = threadIdx.x;
    // stage Wa1 as bf16
    for (int i4 = t; i4 < 128 * 256 / 4; i4 += 256) {
        float4 v = ((const float4*)Wa1)[i4];
        ushort4 u;
        u.x = f2bf(v.x); u.y = f2bf(v.y); u.z = f2bf(v.z); u.w = f2bf(v.w);
        *(ushort4*)&sW2[i4 * 4] = u;
    }
    int cg = t & 31;                 // col group -> 8 cols
    int rg = t >> 5;                 // 0..7 -> rows rg*4..+3 within 32-row chunk
    int j8 = cg * 8;
    float bj[8];
    #pragma unroll
    for (int q = 0; q < 8; q++) bj[q] = ba1[j8 + q];
    int row0 = blockIdx.x * rows_per_block;
    int row_end = min(row0 + rows_per_block, n);
    for (int r = row0; r < row_end; r += 32) {
        int nr = min(32, row_end - r);
        __syncthreads();
        {
            int lrow = t >> 3, seg = t & 7;
            if (lrow < nr) {
                const float4* g = (const float4*)&r_[(size_t)(r + lrow) * 128 + seg * 16];
                float4 v0 = g[0], v1 = g[1], v2 = g[2], v3 = g[3];
                int k0 = seg * 16;
                sT[k0 + 0][lrow] = v0.x; sT[k0 + 1][lrow] = v0.y; sT[k0 + 2][lrow] = v0.z; sT[k0 + 3][lrow] = v0.w;
                sT[k0 + 4][lrow] = v1.x; sT[k0 + 5][lrow] = v1.y; sT[k0 + 6][lrow] = v1.z; sT[k0 + 7][lrow] = v1.w;
                sT[k0 + 8][lrow] = v2.x; sT[k0 + 9][lrow] = v2.y; sT[k0 + 10][lrow] = v2.z; sT[k0 + 11][lrow] = v2.w;
                sT[k0 + 12][lrow] = v3.x; sT[k0 + 13][lrow] = v3.y; sT[k0 + 14][lrow] = v3.z; sT[k0 + 15][lrow] = v3.w;
            }
        }
        __syncthreads();
        float acc[4][8];
        #pragma unroll
        for (int p = 0; p < 4; p++)
            #pragma unroll
            for (int q = 0; q < 8; q++) acc[p][q] = bj[q];
        for (int k = 0; k < 128; k++) {
            uint4 wz = *(const uint4*)&sW2[k * 256 + j8];
            float w0 = bf_lo(wz.x), w1 = bf_hi(wz.x), w2 = bf_lo(wz.y), w3 = bf_hi(wz.y);
            float w4 = bf_lo(wz.z), w5 = bf_hi(wz.z), w6 = bf_lo(wz.w), w7 = bf_hi(wz.w);
            float4 rv = *(const float4*)&sT[k][rg * 4];
            acc[0][0] += rv.x * w0; acc[0][1] += rv.x * w1; acc[0][2] += rv.x * w2; acc[0][3] += rv.x * w3;
            acc[0][4] += rv.x * w4; acc[0][5] += rv.x * w5; acc[0][6] += rv.x * w6; acc[0][7] += rv.x * w7;
            acc[1][0] += rv.y * w0; acc[1][1] += rv.y * w1; acc[1][2] += rv.y * w2; acc[1][3] += rv.y * w3;
            acc[1][4] += rv.y * w4; acc[1][5] += rv.y * w5; acc[1][6] += rv.y * w6; acc[1][7] += rv.y * w7;
            acc[2][0] += rv.z * w0; acc[2][1] += rv.z * w1; acc[2][2] += rv.z * w2; acc[2][3] += rv.z * w3;
            acc[2][4] += rv.z * w4; acc[2][5] += rv.z * w5; acc[2][6] += rv.z * w6; acc[2][7] += rv.z * w7;
            acc[3][0] += rv.w * w0; acc[3][1] += rv.w * w1; acc[3][2] += rv.w * w2; acc[3][3] += rv.w * w3;
            acc[3][4] += rv.w * w4; acc[3][5] += rv.w * w5; acc[3][6] += rv.w * w6; acc[3][7] += rv.w * w7;
        }
        #pragma unroll
        for (int p = 0; p < 4; p++) {
            int row = r + rg * 4 + p;
            float mx = acc[p][0];
            #pragma unroll
            for (int q = 1; q < 8; q++) mx = fmaxf(mx, acc[p][q]);
            mx = fmaxf(mx, __shfl_xor(mx, 16)); mx = fmaxf(mx, __shfl_xor(mx, 8));
            mx = fmaxf(mx, __shfl_xor(mx, 4));  mx = fmaxf(mx, __shfl_xor(mx, 2));
            mx = fmaxf(mx, __shfl_xor(mx, 1));
            float e[8], sm = 0.f;
            #pragma unroll
            for (int q = 0; q < 8; q++) { e[q] = __expf(acc[p][q] - mx); sm += e[q]; }
            sm += __shfl_xor(sm, 16); sm += __shfl_xor(sm, 8); sm += __shfl_xor(sm, 4);
            sm += __shfl_xor(sm, 2);  sm += __shfl_xor(sm, 1);
            if (row < row_end) {
                float inv = 1.0f / sm;
                float4 o0 = make_float4(e[0] * inv, e[1] * inv, e[2] * inv, e[3] * inv);
                float4 o1 = make_float4(e[4] * inv, e[5] * inv, e[6] * inv, e[7] * inv);
                *(float4*)&s1[(size_t)row * 256 + j8] = o0;
                *(float4*)&s1[(size_t)row * 256 + j8 + 4] = o1;
            }
        }
    }
}

// ---------------- x1 = s1^T @ z1: 256 blocks (128 row-splits x 2 col-halves), bf16 z staging ----------------
__global__ __launch_bounds__(512) void k_x1(const float* __restrict__ s1,
                                            const float* __restrict__ z1,
                                            float* __restrict__ part, int n) {
    __shared__ float ss[16][128];            // 8 KB: this block's 128-col half of s1
    __shared__ unsigned short sz[16][128];   // 4 KB: z1 rows as bf16
    int t = threadIdx.x;
    int rs = blockIdx.x >> 1;
    int ch = blockIdx.x & 1;
    int c4 = (t & 31) * 4;       // local col base (0..124)
    int dg = t >> 5;             // 0..15
    int d0 = dg * 8;
    float a[4][8];
    #pragma unroll
    for (int c = 0; c < 4; c++)
        #pragma unroll
        for (int d = 0; d < 8; d++) a[c][d] = 0.f;
    int rows_per_block = (n + X1_SPLIT - 1) / X1_SPLIT;
    int row0 = rs * rows_per_block;
    int row_end = min(row0 + rows_per_block, n);
    int srow = t >> 5, scol4 = (t & 31) * 4;
    for (int r = row0; r < row_end; r += 16) {
        int nb = min(16, row_end - r);
        __syncthreads();
        if (srow < nb) {
            *(float4*)&ss[srow][scol4] = *(const float4*)&s1[(size_t)(r + srow) * 256 + ch * 128 + scol4];
            float4 zv = *(const float4*)&z1[(size_t)(r + srow) * 128 + scol4];
            ushort4 u;
            u.x = f2bf(zv.x); u.y = f2bf(zv.y); u.z = f2bf(zv.z); u.w = f2bf(zv.w);
            *(ushort4*)&sz[srow][scol4] = u;
        }
        __syncthreads();
        for (int i = 0; i < nb; i++) {
            float4 sv = *(const float4*)&ss[i][c4];
            uint4 zz = *(const uint4*)&sz[i][d0];
            float z0 = bf_lo(zz.x), z1f = bf_hi(zz.x), z2 = bf_lo(zz.y), z3 = bf_hi(zz.y);
            float z4 = bf_lo(zz.z), z5 = bf_hi(zz.z), z6 = bf_lo(zz.w), z7 = bf_hi(zz.w);
            float zf[8] = {z0, z1f, z2, z3, z4, z5, z6, z7};
            #pragma unroll
            for (int d = 0; d < 8; d++) {
                a[0][d] += sv.x * zf[d];
                a[1][d] += sv.y * zf[d];
                a[2][d] += sv.z * zf[d];
                a[3][d] += sv.w * zf[d];
            }
        }
    }
    size_t base = (size_t)rs * 32768 + (size_t)(ch * 128 + c4) * 128 + d0;
    #pragma unroll
    for (int c = 0; c < 4; c++) {
        *(float4*)&part[base + (size_t)c * 128]     = make_float4(a[c][0], a[c][1], a[c][2], a[c][3]);
        *(float4*)&part[base + (size_t)c * 128 + 4] = make_float4(a[c][4], a[c][5], a[c][6], a[c][7]);
    }
}

__global__ __launch_bounds__(256) void k_xred(const float* __restrict__ part,
                                              float* __restrict__ x1) {
    int o = blockIdx.x * 256 + threadIdx.x;   // 32768 outputs
    float s = 0.f;
    for (int p = 0; p < X1_SPLIT; p++) s += part[(size_t)p * 32768 + o];
    x1[o] = s;
}

// ---------------- lin2 = x1 @ We2 + be2 ----------------
__global__ __launch_bounds__(256) void k_lin2(const float* __restrict__ x1,
                                              const float* __restrict__ We2,
                                              const float* __restrict__ be2,
                                              float* __restrict__ lin2) {
    int half = threadIdx.x >> 7, j = threadIdx.x & 127;
    int row = blockIdx.x * 2 + half;
    __shared__ float sr[2][128];
    sr[half][j] = x1[row * 128 + j];
    __syncthreads();
    float acc = be2[j];
    #pragma unroll 8
    for (int k = 0; k < 128; k++) acc += sr[half][k] * We2[k * 128 + j];
    lin2[row * 128 + j] = acc;
}

// ---------------- coarse level ----------------
__global__ void k_coarse(const float* __restrict__ lin2, const float* __restrict__ Wa2,
                         const float* __restrict__ ba2,
                         float* __restrict__ s2, float* __restrict__ assign1,
                         float* __restrict__ x2, float* __restrict__ embed0) {
    __shared__ float mrow[128];
    __shared__ float p[32];
    __shared__ float red[2];
    int t = threadIdx.x; // 128 threads
    float s = 0.f;
    for (int i = 0; i < 256; i++) s += lin2[i * 128 + t];
    mrow[t] = s / 256.0f;
    __syncthreads();
    if (t < 32) {
        float z = ba2[t];
        for (int d = 0; d < 128; d++) z += mrow[d] * Wa2[d * 32 + t];
        float mx = z;
        for (int o = 16; o > 0; o >>= 1) mx = fmaxf(mx, __shfl_xor(mx, o, 32));
        float ex = __expf(z - mx);
        float sm = ex;
        for (int o = 16; o > 0; o >>= 1) sm += __shfl_xor(sm, o, 32);
        p[t] = ex / sm;
        assign1[t] = 1.0f;
    }
    __syncthreads();
    for (int i = t; i < 256 * 32; i += 128) s2[i] = p[i & 31];
    for (int i = t; i < 32 * 128; i += 128) {
        int k = i >> 7, d = i & 127;
        x2[i] = 256.0f * p[k] * mrow[d];
    }
    float tot = 0.f;
    for (int i = t; i < 32 * 128; i += 128) {
        int k = i >> 7, d = i & 127;
        tot += 256.0f * p[k] * mrow[d];
    }
    for (int o = 32; o > 0; o >>= 1) tot += __shfl_xor(tot, o);
    if ((t & 63) == 0) red[t >> 6] = tot;
    __syncthreads();
    if (t == 0) embed0[0] = (red[0] + red[1]) / 4096.0f;
}

extern "C" void kernel_launch(void* const* d_in, const int* in_sizes, int n_in,
                              void* d_out, int out_size, void* d_ws, size_t ws_size,
                              hipStream_t stream) {
    const float* feature = (const float*)d_in[0];
    const int*   eidx    = (const int*)d_in[1];
    const float* Wf   = (const float*)d_in[2];
    const float* bf   = (const float*)d_in[3];
    const float* We1  = (const float*)d_in[4];
    const float* be1  = (const float*)d_in[5];
    const float* Wa1  = (const float*)d_in[6];
    const float* ba1  = (const float*)d_in[7];
    const float* attW1= (const float*)d_in[8];
    const float* attb1= (const float*)d_in[9];
    const float* We2  = (const float*)d_in[10];
    const float* be2  = (const float*)d_in[11];
    const float* Wa2  = (const float*)d_in[12];
    const float* ba2  = (const float*)d_in[13];

    const int N = in_sizes[0] / DD;     // 20000
    const int E = in_sizes[1] / 2;      // 340000
    const int* src = eidx;
    const int* dst = eidx + E;

    // d_out layout
    float* out = (float*)d_out;
    float* s1_o      = out;
    float* s2_o      = s1_o + (size_t)N * CC1;
    float* assign1_o = s2_o + CC1 * CC2;
    float* embed3_o  = assign1_o + CC2;
    float* x1_o      = embed3_o + (size_t)N * DD;
    float* x2_o      = x1_o + CC1 * DD;
    float* embed0_o  = x2_o + CC2 * DD;

    // workspace carve (cnt and fill adjacent -> one memset)
    char* w = (char*)d_ws;
    auto alloc = [&](size_t bytes) { void* p = (void*)w; w += ((bytes + 255) / 256) * 256; return p; };
    int* cnt   = (int*)alloc((size_t)N * 4);
    int* fill  = (int*)alloc((size_t)N * 4);
    int* offs  = (int*)alloc((size_t)(N + 1) * 4);
    int* csr   = (int*)alloc((size_t)E * 4);
    float* fold = (float*)alloc(257 * 4);
    float* z1   = (float*)alloc((size_t)N * DD * 4);
    float* a_src = (float*)alloc((size_t)N * 4);
    float* a_dst = (float*)alloc((size_t)N * 4);
    float* lin2  = (float*)alloc((size_t)CC1 * DD * 4);
    size_t agg_bytes = (size_t)N * DD * 4;
    size_t part_bytes = (size_t)X1_SPLIT * CC1 * DD * 4;   // 16.78 MB
    float* agg  = (float*)alloc(agg_bytes > part_bytes ? agg_bytes : part_bytes);
    float* part = agg;   // agg dead by the time k_x1 runs

    hipMemsetAsync(cnt, 0, ((size_t)N * 4 + 255) / 256 * 256 + (size_t)N * 4, stream); // covers cnt+fill

    k_count<<<(E + 255) / 256, 256, 0, stream>>>(dst, cnt, E);
    k_scan<<<1, 1024, 0, stream>>>(cnt, offs, N);
    k_fill<<<(E + 255) / 256, 256, 0, stream>>>(src, dst, offs, fill, csr, E);
    k_fold<<<1, 128, 0, stream>>>(Wa1, ba1, attW1, attb1, fold);

    int segBlocks = (N + 3) / 4;
    k_seg_mean<<<segBlocks, 256, 0, stream>>>(feature, offs, csr, agg, N);
    k_gemm128<0><<<(N + 63) / 64, 256, 0, stream>>>(agg, Wf, bf, embed3_o, nullptr, nullptr, nullptr, N, 64);
    k_seg_mean<<<segBlocks, 256, 0, stream>>>(embed3_o, offs, csr, agg, N);
    k_gemm128<1><<<(N + 63) / 64, 256, 0, stream>>>(agg, We1, be1, z1, fold, a_src, a_dst, N, 64);
    k_att<<<segBlocks, 256, 0, stream>>>(z1, offs, csr, a_src, a_dst, fold, agg, N);
    k_s1<<<(N + 63) / 64, 256, 0, stream>>>(agg, Wa1, ba1, s1_o, N, 64);
    k_x1<<<2 * X1_SPLIT, 512, 0, stream>>>(s1_o, z1, part, N);
    k_xred<<<CC1 * DD / 256, 256, 0, stream>>>(part, x1_o);
    k_lin2<<<CC1 / 2, 256, 0, stream>>>(x1_o, We2, be2, lin2);
    k_coarse<<<1, 128, 0, stream>>>(lin2, Wa2, ba2, s2_o, assign1_o, x2_o, embed0_o);
}

// Round 6
// 353.423 us; speedup vs baseline: 2.8393x; 1.0787x over previous
//
#include <hip/hip_runtime.h>
#include <hip/hip_bf16.h>
#include <math.h>

#define NN 20000
#define DD 128
#define CC1 256
#define CC2 32
#define X1_SPLIT 128

__device__ __forceinline__ unsigned short f2bf(float f) {
    unsigned int b = __float_as_uint(f);
    b = (b + 0x7fffu + ((b >> 16) & 1u)) >> 16;
    return (unsigned short)b;
}
__device__ __forceinline__ float bfu(unsigned short u) { return __uint_as_float((unsigned int)u << 16); }
__device__ __forceinline__ float bf_lo(unsigned int u) { return __uint_as_float(u << 16); }
__device__ __forceinline__ float bf_hi(unsigned int u) { return __uint_as_float(u & 0xffff0000u); }

// ---------------- CSR build ----------------
__global__ void k_count(const int* __restrict__ dst, int* __restrict__ cnt, int E) {
    int e = blockIdx.x * blockDim.x + threadIdx.x;
    if (e < E) atomicAdd(&cnt[dst[e]], 1);
}

__global__ void k_scan(const int* __restrict__ cnt, int* __restrict__ offs, int n) {
    __shared__ int part[1024];
    int t = threadIdx.x;
    int chunk = (n + 1023) / 1024;
    int lo = t * chunk, hi = min(lo + chunk, n);
    int s = 0;
    for (int i = lo; i < hi; i++) s += cnt[i];
    part[t] = s;
    __syncthreads();
    for (int d = 1; d < 1024; d <<= 1) {
        int v = (t >= d) ? part[t - d] : 0;
        __syncthreads();
        part[t] += v;
        __syncthreads();
    }
    int base = (t > 0) ? part[t - 1] : 0;
    for (int i = lo; i < hi; i++) { offs[i] = base; base += cnt[i]; }
    if (t == 1023) offs[n] = part[1023];
}

__global__ void k_fill(const int* __restrict__ src, const int* __restrict__ dst,
                       const int* __restrict__ offs, int* __restrict__ fill,
                       int* __restrict__ csr_src, int E) {
    int e = blockIdx.x * blockDim.x + threadIdx.x;
    if (e < E) {
        int d = dst[e];
        int pos = atomicAdd(&fill[d], 1);
        csr_src[offs[d] + pos] = src[e];
    }
}

// ---------------- bf16 pre-conversion of feature + Wa1 ----------------
__global__ __launch_bounds__(256) void k_prep(const float* __restrict__ feature,
                                              const float* __restrict__ Wa1,
                                              unsigned short* __restrict__ feat_bf,
                                              unsigned short* __restrict__ Wa1b, int nf4) {
    int i = blockIdx.x * 256 + threadIdx.x;
    int tot = nf4 + 128 * 256 / 4;
    if (i >= tot) return;
    float4 v;
    if (i < nf4) v = ((const float4*)feature)[i];
    else         v = ((const float4*)Wa1)[i - nf4];
    ushort4 u;
    u.x = f2bf(v.x); u.y = f2bf(v.y); u.z = f2bf(v.z); u.w = f2bf(v.w);
    if (i < nf4) ((ushort4*)feat_bf)[i] = u;
    else         ((ushort4*)Wa1b)[i - nf4] = u;
}

// ---------------- fold attW1 through Wa1 ----------------
__global__ void k_fold(const float* __restrict__ Wa1, const float* __restrict__ ba1,
                       const float* __restrict__ attW1, const float* __restrict__ attb1,
                       float* __restrict__ fold) {
    int t = threadIdx.x; // 128
    float vs = 0.f, vd = 0.f;
    for (int k = 0; k < CC1; k++) {
        float w = Wa1[t * CC1 + k];
        vs += w * attW1[k];
        vd += w * attW1[CC1 + k];
    }
    fold[t] = vs;
    fold[128 + t] = vd;
    if (t == 0) {
        float c = attb1[0];
        for (int k = 0; k < CC1; k++) c += ba1[k] * (attW1[k] + attW1[CC1 + k]);
        fold[256] = c;
    }
}

// ---------------- per-dst mean over bf16 rows: 4 edges in flight per half-wave ----------------
__global__ __launch_bounds__(256) void k_seg_mean_bf(const unsigned short* __restrict__ in,
                                                     const int* __restrict__ offs,
                                                     const int* __restrict__ csr_src,
                                                     float* __restrict__ out, int n) {
    int wave = (blockIdx.x * blockDim.x + threadIdx.x) >> 6;
    int lane = threadIdx.x & 63;
    if (wave >= n) return;
    int lo = offs[wave], hi = offs[wave + 1];
    int half = lane >> 5, l32 = lane & 31;
    const ushort4* f = (const ushort4*)in;
    float4 acc = make_float4(0.f, 0.f, 0.f, 0.f);
    int i = lo + half;
    while (i + 6 < hi) {
        int s0 = csr_src[i], s1v = csr_src[i + 2], s2 = csr_src[i + 4], s3 = csr_src[i + 6];
        ushort4 v0 = f[(size_t)s0 * 32 + l32];
        ushort4 v1 = f[(size_t)s1v * 32 + l32];
        ushort4 v2 = f[(size_t)s2 * 32 + l32];
        ushort4 v3 = f[(size_t)s3 * 32 + l32];
        acc.x += bfu(v0.x) + bfu(v1.x) + bfu(v2.x) + bfu(v3.x);
        acc.y += bfu(v0.y) + bfu(v1.y) + bfu(v2.y) + bfu(v3.y);
        acc.z += bfu(v0.z) + bfu(v1.z) + bfu(v2.z) + bfu(v3.z);
        acc.w += bfu(v0.w) + bfu(v1.w) + bfu(v2.w) + bfu(v3.w);
        i += 8;
    }
    while (i < hi) {
        ushort4 v = f[(size_t)csr_src[i] * 32 + l32];
        acc.x += bfu(v.x); acc.y += bfu(v.y); acc.z += bfu(v.z); acc.w += bfu(v.w);
        i += 2;
    }
    acc.x += __shfl_xor(acc.x, 32);
    acc.y += __shfl_xor(acc.y, 32);
    acc.z += __shfl_xor(acc.z, 32);
    acc.w += __shfl_xor(acc.w, 32);
    if (half == 0) {
        float inv = 1.0f / (float)max(hi - lo, 1);
        float4 r = make_float4(acc.x * inv, acc.y * inv, acc.z * inv, acc.w * inv);
        ((float4*)out)[(size_t)wave * 32 + l32] = r;
    }
}

// ---------------- row GEMM [n,128]x[128,128]: one 32-row chunk/block, swizzled sT ----------------
// MODE 0: L2-normalize rows -> out f32 + out_bf
// MODE 1: out_bf only (z1 bf16); a_src/a_dst via folded attention vectors
template <int MODE>
__global__ __launch_bounds__(256) void k_gemm128(const float* __restrict__ in,
                                                 const float* __restrict__ W,
                                                 const float* __restrict__ b,
                                                 float* __restrict__ out,
                                                 unsigned short* __restrict__ out_bf,
                                                 const float* __restrict__ fold,
                                                 float* __restrict__ a_src,
                                                 float* __restrict__ a_dst, int n) {
    __shared__ float sW[128 * 128];   // 64 KB
    __shared__ float sT[128 * 32];    // 16 KB, swizzled transposed activations
    int t = threadIdx.x;
    for (int i = t; i < 4096; i += 256) ((float4*)sW)[i] = ((const float4*)W)[i];
    int r0 = blockIdx.x * 32;
    {
        int lrow = t >> 3, seg = t & 7;
        const float4* g = (const float4*)&in[(size_t)(r0 + lrow) * 128 + seg * 16];
        float4 v0 = g[0], v1 = g[1], v2 = g[2], v3 = g[3];
        int base = (((lrow >> 2) ^ seg) << 2) + (lrow & 3);
        int k0 = seg * 16;
        sT[(k0 + 0) * 32 + base] = v0.x; sT[(k0 + 1) * 32 + base] = v0.y;
        sT[(k0 + 2) * 32 + base] = v0.z; sT[(k0 + 3) * 32 + base] = v0.w;
        sT[(k0 + 4) * 32 + base] = v1.x; sT[(k0 + 5) * 32 + base] = v1.y;
        sT[(k0 + 6) * 32 + base] = v1.z; sT[(k0 + 7) * 32 + base] = v1.w;
        sT[(k0 + 8) * 32 + base] = v2.x; sT[(k0 + 9) * 32 + base] = v2.y;
        sT[(k0 + 10) * 32 + base] = v2.z; sT[(k0 + 11) * 32 + base] = v2.w;
        sT[(k0 + 12) * 32 + base] = v3.x; sT[(k0 + 13) * 32 + base] = v3.y;
        sT[(k0 + 14) * 32 + base] = v3.z; sT[(k0 + 15) * 32 + base] = v3.w;
    }
    int lane = t & 63;
    int wv = t >> 6;
    int j4 = (lane & 31) * 4;
    int rg = wv * 2 + (lane >> 5);    // 0..7 -> rows rg*4..rg*4+3
    float bj0 = b[j4], bj1 = b[j4 + 1], bj2 = b[j4 + 2], bj3 = b[j4 + 3];
    float vs0 = 0.f, vs1 = 0.f, vs2 = 0.f, vs3 = 0.f;
    float vd0 = 0.f, vd1 = 0.f, vd2 = 0.f, vd3 = 0.f;
    if (MODE == 1) {
        vs0 = fold[j4]; vs1 = fold[j4 + 1]; vs2 = fold[j4 + 2]; vs3 = fold[j4 + 3];
        vd0 = fold[128 + j4]; vd1 = fold[128 + j4 + 1]; vd2 = fold[128 + j4 + 2]; vd3 = fold[128 + j4 + 3];
    }
    __syncthreads();
    float acc[4][4];
    #pragma unroll
    for (int p = 0; p < 4; p++) { acc[p][0] = bj0; acc[p][1] = bj1; acc[p][2] = bj2; acc[p][3] = bj3; }
    for (int k = 0; k < 128; k++) {
        float4 w4 = *(const float4*)&sW[k * 128 + j4];
        float4 rv = *(const float4*)&sT[k * 32 + ((rg ^ (k >> 4)) << 2)];
        acc[0][0] += rv.x * w4.x; acc[0][1] += rv.x * w4.y; acc[0][2] += rv.x * w4.z; acc[0][3] += rv.x * w4.w;
        acc[1][0] += rv.y * w4.x; acc[1][1] += rv.y * w4.y; acc[1][2] += rv.y * w4.z; acc[1][3] += rv.y * w4.w;
        acc[2][0] += rv.z * w4.x; acc[2][1] += rv.z * w4.y; acc[2][2] += rv.z * w4.z; acc[2][3] += rv.z * w4.w;
        acc[3][0] += rv.w * w4.x; acc[3][1] += rv.w * w4.y; acc[3][2] += rv.w * w4.z; acc[3][3] += rv.w * w4.w;
    }
    #pragma unroll
    for (int p = 0; p < 4; p++) {
        int row = r0 + rg * 4 + p;
        if (MODE == 0) {
            float ss_ = acc[p][0] * acc[p][0] + acc[p][1] * acc[p][1] +
                        acc[p][2] * acc[p][2] + acc[p][3] * acc[p][3];
            ss_ += __shfl_xor(ss_, 16); ss_ += __shfl_xor(ss_, 8);
            ss_ += __shfl_xor(ss_, 4);  ss_ += __shfl_xor(ss_, 2); ss_ += __shfl_xor(ss_, 1);
            float scale = 1.0f / fmaxf(sqrtf(ss_), 1e-12f);
            float o0 = acc[p][0] * scale, o1 = acc[p][1] * scale, o2 = acc[p][2] * scale, o3 = acc[p][3] * scale;
            *(float4*)&out[(size_t)row * 128 + j4] = make_float4(o0, o1, o2, o3);
            ushort4 u; u.x = f2bf(o0); u.y = f2bf(o1); u.z = f2bf(o2); u.w = f2bf(o3);
            ((ushort4*)out_bf)[(size_t)row * 32 + (j4 >> 2)] = u;
        } else {
            ushort4 u; u.x = f2bf(acc[p][0]); u.y = f2bf(acc[p][1]); u.z = f2bf(acc[p][2]); u.w = f2bf(acc[p][3]);
            ((ushort4*)out_bf)[(size_t)row * 32 + (j4 >> 2)] = u;
            float ps = acc[p][0] * vs0 + acc[p][1] * vs1 + acc[p][2] * vs2 + acc[p][3] * vs3;
            float pd = acc[p][0] * vd0 + acc[p][1] * vd1 + acc[p][2] * vd2 + acc[p][3] * vd3;
            ps += __shfl_xor(ps, 16); ps += __shfl_xor(ps, 8); ps += __shfl_xor(ps, 4);
            ps += __shfl_xor(ps, 2);  ps += __shfl_xor(ps, 1);
            pd += __shfl_xor(pd, 16); pd += __shfl_xor(pd, 8); pd += __shfl_xor(pd, 4);
            pd += __shfl_xor(pd, 2);  pd += __shfl_xor(pd, 1);
            if ((lane & 31) == 0) { a_src[row] = ps; a_dst[row] = pd; }
        }
    }
}

// ---------------- sparse GAT core: fused pass over bf16 z1, 4 edges in flight ----------------
__global__ __launch_bounds__(256) void k_att(const unsigned short* __restrict__ z1b,
                                             const int* __restrict__ offs,
                                             const int* __restrict__ csr_src,
                                             const float* __restrict__ a_src,
                                             const float* __restrict__ a_dst,
                                             const float* __restrict__ fold,
                                             float* __restrict__ r, int n) {
    int wave = (blockIdx.x * blockDim.x + threadIdx.x) >> 6;
    int lane = threadIdx.x & 63;
    if (wave >= n) return;
    int lo = offs[wave], hi = offs[wave + 1];
    float C0 = fold[256] + a_dst[wave];
    int half = lane >> 5, l32 = lane & 31;
    const ushort4* z4 = (const ushort4*)z1b;
    float4 acc = make_float4(0.f, 0.f, 0.f, 0.f);
    float den = 0.f;
    int i = lo + half;
    while (i + 6 < hi) {
        int s0 = csr_src[i], s1v = csr_src[i + 2], s2 = csr_src[i + 4], s3 = csr_src[i + 6];
        float a0 = a_src[s0], a1 = a_src[s1v], a2 = a_src[s2], a3 = a_src[s3];
        ushort4 v0 = z4[(size_t)s0 * 32 + l32];
        ushort4 v1 = z4[(size_t)s1v * 32 + l32];
        ushort4 v2 = z4[(size_t)s2 * 32 + l32];
        ushort4 v3 = z4[(size_t)s3 * 32 + l32];
        float e0 = a0 + C0; e0 = e0 > 0.f ? e0 : 0.01f * e0;
        float e1 = a1 + C0; e1 = e1 > 0.f ? e1 : 0.01f * e1;
        float e2 = a2 + C0; e2 = e2 > 0.f ? e2 : 0.01f * e2;
        float e3 = a3 + C0; e3 = e3 > 0.f ? e3 : 0.01f * e3;
        float al0 = __expf(fminf(e0, 60.f)), al1 = __expf(fminf(e1, 60.f));
        float al2 = __expf(fminf(e2, 60.f)), al3 = __expf(fminf(e3, 60.f));
        den += (al0 + al1) + (al2 + al3);
        acc.x += al0 * bfu(v0.x) + al1 * bfu(v1.x) + al2 * bfu(v2.x) + al3 * bfu(v3.x);
        acc.y += al0 * bfu(v0.y) + al1 * bfu(v1.y) + al2 * bfu(v2.y) + al3 * bfu(v3.y);
        acc.z += al0 * bfu(v0.z) + al1 * bfu(v1.z) + al2 * bfu(v2.z) + al3 * bfu(v3.z);
        acc.w += al0 * bfu(v0.w) + al1 * bfu(v1.w) + al2 * bfu(v2.w) + al3 * bfu(v3.w);
        i += 8;
    }
    while (i < hi) {
        int s = csr_src[i];
        float a = a_src[s];
        ushort4 v = z4[(size_t)s * 32 + l32];
        float e = a + C0; e = e > 0.f ? e : 0.01f * e;
        float al = __expf(fminf(e, 60.f));
        den += al;
        acc.x += al * bfu(v.x); acc.y += al * bfu(v.y);
        acc.z += al * bfu(v.z); acc.w += al * bfu(v.w);
        i += 2;
    }
    den += __shfl_xor(den, 32);
    acc.x += __shfl_xor(acc.x, 32);
    acc.y += __shfl_xor(acc.y, 32);
    acc.z += __shfl_xor(acc.z, 32);
    acc.w += __shfl_xor(acc.w, 32);
    if (half == 0) {
        float invden = 1.0f / den;
        float4 o = make_float4(acc.x * invden, acc.y * invden, acc.z * invden, acc.w * invden);
        ((float4*)r)[(size_t)wave * 32 + l32] = o;
    }
}

// ---------------- s1 = softmax(r @ Wa1 + ba1): one chunk/block, bf16 W copy, swizzled sT ----------------
__global__ __launch_bounds__(256) void k_s1(const float* __restrict__ r_,
                                            const unsigned short* __restrict__ Wa1b,
                                            const float* __restrict__ ba1,
                                            float* __restrict__ s1, int n) {
    __shared__ unsigned short sW2[128 * 256];  // 64 KB bf16 (raw copy, no cvt)
    __shared__ float sT[128 * 32];             // 16 KB swizzled
    int t = threadIdx.x;
    {
        // 128*256 ushorts = 4096 uint4; 256 threads x 16 iterations
        const uint4* g = (const uint4*)Wa1b;
        uint4* d = (uint4*)sW2;
        #pragma unroll
        for (int i = 0; i < 16; i++) d[t + i * 256] = g[t + i * 256];
    }
    int r0 = blockIdx.x * 32;
    {
        int lrow = t >> 3, seg = t & 7;
        const float4* g = (const float4*)&r_[(size_t)(r0 + lrow) * 128 + seg * 16];
        float4 v0 = g[0], v1 = g[1], v2 = g[2], v3 = g[3];
        int base = (((lrow >> 2) ^ seg) << 2) + (lrow & 3);
        int k0 = seg * 16;
        sT[(k0 + 0) * 32 + base] = v0.x; sT[(k0 + 1) * 32 + base] = v0.y;
        sT[(k0 + 2) * 32 + base] = v0.z; sT[(k0 + 3) * 32 + base] = v0.w;
        sT[(k0 + 4) * 32 + base] = v1.x; sT[(k0 + 5) * 32 + base] = v1.y;
        sT[(k0 + 6) * 32 + base] = v1.z; sT[(k0 + 7) * 32 + base] = v1.w;
        sT[(k0 + 8) * 32 + base] = v2.x; sT[(k0 + 9) * 32 + base] = v2.y;
        sT[(k0 + 10) * 32 + base] = v2.z; sT[(k0 + 11) * 32 + base] = v2.w;
        sT[(k0 + 12) * 32 + base] = v3.x; sT[(k0 + 13) * 32 + base] = v3.y;
        sT[(k0 + 14) * 32 + base] = v3.z; sT[(k0 + 15) * 32 + base] = v3.w;
    }
    int cg = t & 31, rg = t >> 5;
    int j8 = cg * 8;
    float bj[8];
    #pragma unroll
    for (int q = 0; q < 8; q++) bj[q] = ba1[j8 + q];
    __syncthreads();
    float acc[4][8];
    #pragma unroll
    for (int p = 0; p < 4; p++)
        #pragma unroll
        for (int q = 0; q < 8; q++) acc[p][q] = bj[q];
    for (int k = 0; k < 128; k++) {
        uint4 wz = *(const uint4*)&sW2[k * 256 + j8];
        float w0 = bf_lo(wz.x), w1 = bf_hi(wz.x), w2 = bf_lo(wz.y), w3 = bf_hi(wz.y);
        float w4 = bf_lo(wz.z), w5 = bf_hi(wz.z), w6 = bf_lo(wz.w), w7 = bf_hi(wz.w);
        float4 rv = *(const float4*)&sT[k * 32 + ((rg ^ (k >> 4)) << 2)];
        acc[0][0] += rv.x * w0; acc[0][1] += rv.x * w1; acc[0][2] += rv.x * w2; acc[0][3] += rv.x * w3;
        acc[0][4] += rv.x * w4; acc[0][5] += rv.x * w5; acc[0][6] += rv.x * w6; acc[0][7] += rv.x * w7;
        acc[1][0] += rv.y * w0; acc[1][1] += rv.y * w1; acc[1][2] += rv.y * w2; acc[1][3] += rv.y * w3;
        acc[1][4] += rv.y * w4; acc[1][5] += rv.y * w5; acc[1][6] += rv.y * w6; acc[1][7] += rv.y * w7;
        acc[2][0] += rv.z * w0; acc[2][1] += rv.z * w1; acc[2][2] += rv.z * w2; acc[2][3] += rv.z * w3;
        acc[2][4] += rv.z * w4; acc[2][5] += rv.z * w5; acc[2][6] += rv.z * w6; acc[2][7] += rv.z * w7;
        acc[3][0] += rv.w * w0; acc[3][1] += rv.w * w1; acc[3][2] += rv.w * w2; acc[3][3] += rv.w * w3;
        acc[3][4] += rv.w * w4; acc[3][5] += rv.w * w5; acc[3][6] += rv.w * w6; acc[3][7] += rv.w * w7;
    }
    #pragma unroll
    for (int p = 0; p < 4; p++) {
        int row = r0 + rg * 4 + p;
        float mx = acc[p][0];
        #pragma unroll
        for (int q = 1; q < 8; q++) mx = fmaxf(mx, acc[p][q]);
        mx = fmaxf(mx, __shfl_xor(mx, 16)); mx = fmaxf(mx, __shfl_xor(mx, 8));
        mx = fmaxf(mx, __shfl_xor(mx, 4));  mx = fmaxf(mx, __shfl_xor(mx, 2));
        mx = fmaxf(mx, __shfl_xor(mx, 1));
        float e[8], sm = 0.f;
        #pragma unroll
        for (int q = 0; q < 8; q++) { e[q] = __expf(acc[p][q] - mx); sm += e[q]; }
        sm += __shfl_xor(sm, 16); sm += __shfl_xor(sm, 8); sm += __shfl_xor(sm, 4);
        sm += __shfl_xor(sm, 2);  sm += __shfl_xor(sm, 1);
        float inv = 1.0f / sm;
        *(float4*)&s1[(size_t)row * 256 + j8]     = make_float4(e[0] * inv, e[1] * inv, e[2] * inv, e[3] * inv);
        *(float4*)&s1[(size_t)row * 256 + j8 + 4] = make_float4(e[4] * inv, e[5] * inv, e[6] * inv, e[7] * inv);
    }
}

// ---------------- x1 = s1^T @ z1: 256 blocks (128 row-splits x 2 col-halves), bf16 z from prep ----------------
__global__ __launch_bounds__(512) void k_x1(const float* __restrict__ s1,
                                            const unsigned short* __restrict__ z1b,
                                            float* __restrict__ part, int n) {
    __shared__ float ss[16][128];            // 8 KB
    __shared__ unsigned short sz[16][128];   // 4 KB
    int t = threadIdx.x;
    int rs = blockIdx.x >> 1;
    int ch = blockIdx.x & 1;
    int c4 = (t & 31) * 4;
    int dg = t >> 5;
    int d0 = dg * 8;
    float a[4][8];
    #pragma unroll
    for (int c = 0; c < 4; c++)
        #pragma unroll
        for (int d = 0; d < 8; d++) a[c][d] = 0.f;
    int rows_per_block = (n + X1_SPLIT - 1) / X1_SPLIT;
    int row0 = rs * rows_per_block;
    int row_end = min(row0 + rows_per_block, n);
    int srow = t >> 5, scol4 = (t & 31) * 4;
    for (int r = row0; r < row_end; r += 16) {
        int nb = min(16, row_end - r);
        __syncthreads();
        if (srow < nb) {
            *(float4*)&ss[srow][scol4] = *(const float4*)&s1[(size_t)(r + srow) * 256 + ch * 128 + scol4];
            ((ushort4*)&sz[srow][0])[t & 31] = ((const ushort4*)z1b)[(size_t)(r + srow) * 32 + (t & 31)];
        }
        __syncthreads();
        for (int i = 0; i < nb; i++) {
            float4 sv = *(const float4*)&ss[i][c4];
            uint4 zz = *(const uint4*)&sz[i][d0];
            float zf[8];
            zf[0] = bf_lo(zz.x); zf[1] = bf_hi(zz.x); zf[2] = bf_lo(zz.y); zf[3] = bf_hi(zz.y);
            zf[4] = bf_lo(zz.z); zf[5] = bf_hi(zz.z); zf[6] = bf_lo(zz.w); zf[7] = bf_hi(zz.w);
            #pragma unroll
            for (int d = 0; d < 8; d++) {
                a[0][d] += sv.x * zf[d];
                a[1][d] += sv.y * zf[d];
                a[2][d] += sv.z * zf[d];
                a[3][d] += sv.w * zf[d];
            }
        }
    }
    size_t base = (size_t)rs * 32768 + (size_t)(ch * 128 + c4) * 128 + d0;
    #pragma unroll
    for (int c = 0; c < 4; c++) {
        *(float4*)&part[base + (size_t)c * 128]     = make_float4(a[c][0], a[c][1], a[c][2], a[c][3]);
        *(float4*)&part[base + (size_t)c * 128 + 4] = make_float4(a[c][4], a[c][5], a[c][6], a[c][7]);
    }
}

__global__ __launch_bounds__(256) void k_xred(const float* __restrict__ part,
                                              float* __restrict__ x1) {
    int o = blockIdx.x * 256 + threadIdx.x;   // 32768 outputs
    float s = 0.f;
    for (int p = 0; p < X1_SPLIT; p++) s += part[(size_t)p * 32768 + o];
    x1[o] = s;
}

// ---------------- lin2 = x1 @ We2 + be2 ----------------
__global__ __launch_bounds__(256) void k_lin2(const float* __restrict__ x1,
                                              const float* __restrict__ We2,
                                              const float* __restrict__ be2,
                                              float* __restrict__ lin2) {
    int half = threadIdx.x >> 7, j = threadIdx.x & 127;
    int row = blockIdx.x * 2 + half;
    __shared__ float sr[2][128];
    sr[half][j] = x1[row * 128 + j];
    __syncthreads();
    float acc = be2[j];
    #pragma unroll 8
    for (int k = 0; k < 128; k++) acc += sr[half][k] * We2[k * 128 + j];
    lin2[row * 128 + j] = acc;
}

// ---------------- coarse level ----------------
__global__ void k_coarse(const float* __restrict__ lin2, const float* __restrict__ Wa2,
                         const float* __restrict__ ba2,
                         float* __restrict__ s2, float* __restrict__ assign1,
                         float* __restrict__ x2, float* __restrict__ embed0) {
    __shared__ float mrow[128];
    __shared__ float p[32];
    __shared__ float red[2];
    int t = threadIdx.x; // 128 threads
    float s = 0.f;
    for (int i = 0; i < 256; i++) s += lin2[i * 128 + t];
    mrow[t] = s / 256.0f;
    __syncthreads();
    if (t < 32) {
        float z = ba2[t];
        for (int d = 0; d < 128; d++) z += mrow[d] * Wa2[d * 32 + t];
        float mx = z;
        for (int o = 16; o > 0; o >>= 1) mx = fmaxf(mx, __shfl_xor(mx, o, 32));
        float ex = __expf(z - mx);
        float sm = ex;
        for (int o = 16; o > 0; o >>= 1) sm += __shfl_xor(sm, o, 32);
        p[t] = ex / sm;
        assign1[t] = 1.0f;
    }
    __syncthreads();
    for (int i = t; i < 256 * 32; i += 128) s2[i] = p[i & 31];
    for (int i = t; i < 32 * 128; i += 128) {
        int k = i >> 7, d = i & 127;
        x2[i] = 256.0f * p[k] * mrow[d];
    }
    float tot = 0.f;
    for (int i = t; i < 32 * 128; i += 128) {
        int k = i >> 7, d = i & 127;
        tot += 256.0f * p[k] * mrow[d];
    }
    for (int o = 32; o > 0; o >>= 1) tot += __shfl_xor(tot, o);
    if ((t & 63) == 0) red[t >> 6] = tot;
    __syncthreads();
    if (t == 0) embed0[0] = (red[0] + red[1]) / 4096.0f;
}

extern "C" void kernel_launch(void* const* d_in, const int* in_sizes, int n_in,
                              void* d_out, int out_size, void* d_ws, size_t ws_size,
                              hipStream_t stream) {
    const float* feature = (const float*)d_in[0];
    const int*   eidx    = (const int*)d_in[1];
    const float* Wf   = (const float*)d_in[2];
    const float* bf   = (const float*)d_in[3];
    const float* We1  = (const float*)d_in[4];
    const float* be1  = (const float*)d_in[5];
    const float* Wa1  = (const float*)d_in[6];
    const float* ba1  = (const float*)d_in[7];
    const float* attW1= (const float*)d_in[8];
    const float* attb1= (const float*)d_in[9];
    const float* We2  = (const float*)d_in[10];
    const float* be2  = (const float*)d_in[11];
    const float* Wa2  = (const float*)d_in[12];
    const float* ba2  = (const float*)d_in[13];

    const int N = in_sizes[0] / DD;     // 20000
    const int E = in_sizes[1] / 2;      // 340000
    const int* src = eidx;
    const int* dst = eidx + E;

    // d_out layout
    float* out = (float*)d_out;
    float* s1_o      = out;
    float* s2_o      = s1_o + (size_t)N * CC1;
    float* assign1_o = s2_o + CC1 * CC2;
    float* embed3_o  = assign1_o + CC2;
    float* x1_o      = embed3_o + (size_t)N * DD;
    float* x2_o      = x1_o + CC1 * DD;
    float* embed0_o  = x2_o + CC2 * DD;

    // workspace carve (cnt and fill adjacent -> one memset)
    char* w = (char*)d_ws;
    auto alloc = [&](size_t bytes) { void* p = (void*)w; w += ((bytes + 255) / 256) * 256; return p; };
    int* cnt   = (int*)alloc((size_t)N * 4);
    int* fill  = (int*)alloc((size_t)N * 4);
    int* offs  = (int*)alloc((size_t)(N + 1) * 4);
    int* csr   = (int*)alloc((size_t)E * 4);
    float* fold = (float*)alloc(257 * 4);
    unsigned short* feat_bf = (unsigned short*)alloc((size_t)N * DD * 2);
    unsigned short* e3_bf   = (unsigned short*)alloc((size_t)N * DD * 2);
    unsigned short* z1b     = (unsigned short*)alloc((size_t)N * DD * 2);
    unsigned short* Wa1b    = (unsigned short*)alloc((size_t)128 * 256 * 2);
    float* a_src = (float*)alloc((size_t)N * 4);
    float* a_dst = (float*)alloc((size_t)N * 4);
    float* lin2  = (float*)alloc((size_t)CC1 * DD * 4);
    size_t agg_bytes = (size_t)N * DD * 4;
    size_t part_bytes = (size_t)X1_SPLIT * CC1 * DD * 4;   // 16.78 MB
    float* agg  = (float*)alloc(agg_bytes > part_bytes ? agg_bytes : part_bytes);
    float* part = agg;   // agg dead by the time k_x1 runs

    hipMemsetAsync(cnt, 0, ((size_t)N * 4 + 255) / 256 * 256 + (size_t)N * 4, stream); // covers cnt+fill

    k_count<<<(E + 255) / 256, 256, 0, stream>>>(dst, cnt, E);
    k_scan<<<1, 1024, 0, stream>>>(cnt, offs, N);
    k_fill<<<(E + 255) / 256, 256, 0, stream>>>(src, dst, offs, fill, csr, E);
    int nf4 = N * DD / 4;
    k_prep<<<(nf4 + 128 * 256 / 4 + 255) / 256, 256, 0, stream>>>(feature, Wa1, feat_bf, Wa1b, nf4);
    k_fold<<<1, 128, 0, stream>>>(Wa1, ba1, attW1, attb1, fold);

    int segBlocks = (N + 3) / 4;
    int chunkBlocks = N / 32;   // 625, exact
    // mean(feature_bf) -> agg
    k_seg_mean_bf<<<segBlocks, 256, 0, stream>>>(feat_bf, offs, csr, agg, N);
    // embed3 = normalize(agg @ Wf + bf) (f32 out + bf16 copy)
    k_gemm128<0><<<chunkBlocks, 256, 0, stream>>>(agg, Wf, bf, embed3_o, e3_bf, nullptr, nullptr, nullptr, N);
    // mean(embed3_bf) -> agg
    k_seg_mean_bf<<<segBlocks, 256, 0, stream>>>(e3_bf, offs, csr, agg, N);
    // z1 (bf16) = agg @ We1 + be1 ; a_src/a_dst
    k_gemm128<1><<<chunkBlocks, 256, 0, stream>>>(agg, We1, be1, nullptr, z1b, fold, a_src, a_dst, N);
    // attention -> r (reuse agg)
    k_att<<<segBlocks, 256, 0, stream>>>(z1b, offs, csr, a_src, a_dst, fold, agg, N);
    // s1 = softmax(r @ Wa1 + ba1)
    k_s1<<<chunkBlocks, 256, 0, stream>>>(agg, Wa1b, ba1, s1_o, N);
    // x1 = s1^T @ z1
    k_x1<<<2 * X1_SPLIT, 512, 0, stream>>>(s1_o, z1b, part, N);
    k_xred<<<CC1 * DD / 256, 256, 0, stream>>>(part, x1_o);
    k_lin2<<<CC1 / 2, 256, 0, stream>>>(x1_o, We2, be2, lin2);
    k_coarse<<<1, 128, 0, stream>>>(lin2, Wa2, ba2, s2_o, assign1_o, x2_o, embed0_o);
}